// Round 7
// baseline (241.824 us; speedup 1.0000x reference)
//
#include <hip/hip_runtime.h>
#include <hip/hip_bf16.h>
#include <math.h>

// Problem constants: B=4, L=96, D=256, H=8, hd=32, FF=1024. M = B*L*L = 36864.
#define M_ROWS 36864

typedef __bf16 bf16x8 __attribute__((ext_vector_type(8)));
typedef float f32x4 __attribute__((ext_vector_type(4)));

__device__ __forceinline__ void gload16(const void* g, void* l) {
  __builtin_amdgcn_global_load_lds((const __attribute__((address_space(1))) void*)g,
                                   (__attribute__((address_space(3))) void*)l, 16, 0, 0);
}

// ---------------- convert table fp32 -> bf16 (8 elems/thread) ----------------
__global__ __launch_bounds__(256) void cvt_bf16_kernel(const float* __restrict__ X,
                                                       __bf16* __restrict__ Y, int n8) {
  int i = blockIdx.x * 256 + threadIdx.x;
  if (i >= n8) return;
  const float4 a = ((const float4*)X)[(size_t)i * 2];
  const float4 b = ((const float4*)X)[(size_t)i * 2 + 1];
  bf16x8 o = {(__bf16)a.x, (__bf16)a.y, (__bf16)a.z, (__bf16)a.w,
              (__bf16)b.x, (__bf16)b.y, (__bf16)b.z, (__bf16)b.w};
  *(bf16x8*)&Y[(size_t)i * 8] = o;
}

// ---------------- pack + transpose weights to bf16 B^T [N,K] ----------------
__global__ __launch_bounds__(256) void pack_w_kernel(
    const float* __restrict__ Wq, const float* __restrict__ Wk, const float* __restrict__ Wv,
    const float* __restrict__ Wo, const float* __restrict__ W1, const float* __restrict__ W2,
    const float* __restrict__ bq, const float* __restrict__ bk, const float* __restrict__ bv,
    __bf16* __restrict__ Wqkv_t, __bf16* __restrict__ Wo_t,
    __bf16* __restrict__ W1_t, __bf16* __restrict__ W2_t, float* __restrict__ bqkv) {
  int idx = blockIdx.x * 256 + threadIdx.x;
  const int S1 = 768 * 256, S2 = 256 * 256, S3 = 1024 * 256;
  if (idx < S1) {
    int n = idx / 256, k = idx % 256;
    int sel = n >> 8, nn = n & 255;
    const float* W = (sel == 0) ? Wq : (sel == 1) ? Wk : Wv;
    Wqkv_t[idx] = (__bf16)W[k * 256 + nn];
  } else if (idx < S1 + S2) {
    int j = idx - S1; int n = j / 256, k = j % 256;
    Wo_t[j] = (__bf16)Wo[k * 256 + n];
  } else if (idx < S1 + S2 + S3) {
    int j = idx - S1 - S2; int n = j / 256, k = j % 256;
    W1_t[j] = (__bf16)W1[k * 1024 + n];
  } else {
    int j = idx - S1 - S2 - S3; int n = j / 1024, k = j % 1024;
    W2_t[j] = (__bf16)W2[k * 256 + n];
  }
  if (idx < 768) {
    int sel = idx >> 8, jj = idx & 255;
    const float* bsrc = (sel == 0) ? bq : (sel == 1) ? bk : bv;
    bqkv[idx] = bsrc[jj];
  }
}

// ---------------- unified 8-wave MFMA GEMM: BM=128 x BN=256, BK=32 ------------
// 512 threads, wave grid 2M x 4N, per-wave 64x64 (4x4 frags of 16x16x32).
// K-loop: 4-buffer ring, prefetch depth 3, ONE raw s_barrier per phase,
// counted vmcnt(6) (never 0 until tail) -- T3/T4 recipe.
// EPI: 0 = bias -> bf16, 1 = bias+relu -> bf16,
//      2 = bias + fp32 resid + LayerNorm -> fp32 (+ optional bf16 copy). N must be 256.
template <int EPI, bool EMIT_BF16>
__global__ __launch_bounds__(512) void gemm8_kernel(
    const __bf16* __restrict__ A, const __bf16* __restrict__ Bt,
    const float* __restrict__ bias, const float* __restrict__ resid,
    const float* __restrict__ gamma, const float* __restrict__ beta,
    void* __restrict__ Y, __hip_bfloat16* __restrict__ Yb, int N, int K) {
  __shared__ __bf16 As[4][128 * 32];
  __shared__ __bf16 Bs[4][256 * 32];
  __shared__ float red[2][4][128];   // LN scratch (EPI==2)
  const int tid = threadIdx.x;
  const int lane = tid & 63, wv = tid >> 6;
  const int wm = wv >> 2, wn = wv & 3;
  // XCD-chunked block swizzle (nwg divisible by 8 for all our grids)
  const int gx = gridDim.x;
  const int nwg = gx * gridDim.y;
  int lin = blockIdx.y * gx + blockIdx.x;
  lin = (lin & 7) * (nwg >> 3) + (lin >> 3);
  const int n0 = (lin % gx) * 256;
  const int m0 = (lin / gx) * 128;
  const int fr = lane & 15, g = lane >> 4;
  const int arow = tid >> 2;                             // 0..127
  const int gcol = ((tid & 3) ^ ((tid >> 3) & 3)) * 8;   // pre-swizzled source colseg

  f32x4 acc[4][4] = {};
  const int nph = K >> 5;   // >= 8 for all our calls

#define STAGE8(buf, kb)                                                   \
  {                                                                       \
    gload16(A + (size_t)(m0 + arow) * K + (kb) + gcol,                    \
            &As[buf][wv * 512]);                                          \
    gload16(Bt + (size_t)(n0 + arow) * K + (kb) + gcol,                   \
            &Bs[buf][wv * 512]);                                          \
    gload16(Bt + (size_t)(n0 + 128 + arow) * K + (kb) + gcol,             \
            &Bs[buf][4096 + wv * 512]);                                   \
  }

  // prologue: 3 stages in flight (9 loads/thread)
  STAGE8(0, 0)
  STAGE8(1, 32)
  STAGE8(2, 64)

  for (int p = 0; p < nph; ++p) {
    const int rem = nph - 1 - p;
    // wait: stage(p) landed (2 stages = 6 loads may remain in flight); own ds_reads done
    if (rem >= 2)      asm volatile("s_waitcnt vmcnt(6) lgkmcnt(0)" ::: "memory");
    else if (rem == 1) asm volatile("s_waitcnt vmcnt(3) lgkmcnt(0)" ::: "memory");
    else               asm volatile("s_waitcnt vmcnt(0) lgkmcnt(0)" ::: "memory");
    __builtin_amdgcn_s_barrier();        // raw: no vmcnt drain
    __builtin_amdgcn_sched_barrier(0);
    if (p + 3 < nph) STAGE8((p + 3) & 3, (p + 3) * 32)   // loads span phases
    const int cur = p & 3;
    const int cs = (g ^ ((fr >> 1) & 3)) * 8;            // read-side un-swizzle
    bf16x8 av[4], bv[4];
#pragma unroll
    for (int mi = 0; mi < 4; ++mi)
      av[mi] = *reinterpret_cast<const bf16x8*>(&As[cur][(wm * 64 + mi * 16 + fr) * 32 + cs]);
#pragma unroll
    for (int ni = 0; ni < 4; ++ni)
      bv[ni] = *reinterpret_cast<const bf16x8*>(&Bs[cur][(wn * 64 + ni * 16 + fr) * 32 + cs]);
#pragma unroll
    for (int mi = 0; mi < 4; ++mi)
#pragma unroll
      for (int ni = 0; ni < 4; ++ni)
        acc[mi][ni] = __builtin_amdgcn_mfma_f32_16x16x32_bf16(av[mi], bv[ni], acc[mi][ni], 0, 0, 0);
  }
#undef STAGE8

  if (EPI < 2) {
    // ---- plain epilogue: bias (+relu), bf16 out ----
    const int crow = m0 + wm * 64 + g * 4;
    const int ccol = n0 + wn * 64 + fr;
    __hip_bfloat16* ob = (__hip_bfloat16*)Y;
#pragma unroll
    for (int mi = 0; mi < 4; ++mi) {
#pragma unroll
      for (int ni = 0; ni < 4; ++ni) {
        const int col = ccol + ni * 16;
        const float bb = bias[col];
#pragma unroll
        for (int r = 0; r < 4; ++r) {
          const int row = crow + mi * 16 + r;
          float v = acc[mi][ni][r] + bb;
          if (EPI == 1) v = fmaxf(v, 0.f);
          ob[(size_t)row * N + col] = __float2bfloat16(v);
        }
      }
    }
  } else {
    // ---- LN epilogue: v = acc + bias + resid; LayerNorm over 256 cols ----
    float* Yf = (float*)Y;
    const int colb = wn * 64 + fr;  // + ni*16
    float bb[4], gg[4], be[4];
#pragma unroll
    for (int ni = 0; ni < 4; ++ni) {
      bb[ni] = bias[colb + ni * 16];
      gg[ni] = gamma[colb + ni * 16];
      be[ni] = beta[colb + ni * 16];
    }
#pragma unroll
    for (int mi = 0; mi < 4; ++mi) {
#pragma unroll
      for (int r = 0; r < 4; ++r) {
        const int lr = wm * 64 + mi * 16 + g * 4 + r;
        const size_t grow = (size_t)(m0 + lr) * 256;
        float s = 0.f, q = 0.f;
#pragma unroll
        for (int ni = 0; ni < 4; ++ni) {
          float v = acc[mi][ni][r] + bb[ni] + resid[grow + colb + ni * 16];
          acc[mi][ni][r] = v;
          s += v; q += v * v;
        }
#pragma unroll
        for (int o = 8; o > 0; o >>= 1) { s += __shfl_xor(s, o); q += __shfl_xor(q, o); }
        if (fr == 0) { red[0][wn][lr] = s; red[1][wn][lr] = q; }
      }
    }
    __syncthreads();
#pragma unroll
    for (int mi = 0; mi < 4; ++mi) {
#pragma unroll
      for (int r = 0; r < 4; ++r) {
        const int lr = wm * 64 + mi * 16 + g * 4 + r;
        const size_t grow = (size_t)(m0 + lr) * 256;
        const float s = red[0][0][lr] + red[0][1][lr] + red[0][2][lr] + red[0][3][lr];
        const float q = red[1][0][lr] + red[1][1][lr] + red[1][2][lr] + red[1][3][lr];
        const float mean = s * (1.0f / 256.0f);
        const float var = q * (1.0f / 256.0f) - mean * mean;
        const float inv = rsqrtf(var + 1e-5f);
#pragma unroll
        for (int ni = 0; ni < 4; ++ni) {
          const float y = (acc[mi][ni][r] - mean) * inv * gg[ni] + be[ni];
          Yf[grow + colb + ni * 16] = y;
          if (EMIT_BF16) Yb[grow + colb + ni * 16] = __float2bfloat16(y);
        }
      }
    }
  }
}

// ---------------- MFMA attention: one block per (b,h,x), 6 waves ----------------
__global__ __launch_bounds__(384) void attn_mfma_kernel(
    const __bf16* __restrict__ qkv, const float* __restrict__ depm,
    const float* __restrict__ Wdep, const float* __restrict__ bdep,
    __hip_bfloat16* __restrict__ ctx) {
  __shared__ __bf16 Qs[96][40];
  __shared__ __bf16 Ks[96][40];
  __shared__ __bf16 Vt[32][104];
  __shared__ __bf16 Ps[6][16][104];
  // XCD swizzle: 8 heads of one (b,x) slab -> consecutive -> same XCD L2
  int lin = blockIdx.x;
  lin = (lin & 7) * 384 + (lin >> 3);
  const int h = lin & 7;
  const int sx = lin >> 3;
  const int x = sx % 96;
  const int b = sx / 96;
  const int tid = threadIdx.x;
  const size_t slab = (size_t)(b * 96 + x) * 96;
  const size_t base = slab * 768 + h * 32;
#pragma unroll
  for (int t = 0; t < 3; ++t) {
    const int idx = tid + t * 384;
    const int r = idx / 12, rem = idx % 12, mat = rem >> 2, seg = rem & 3;
    const int d0 = seg * 8;
    bf16x8 v8 = *(const bf16x8*)&qkv[base + (size_t)r * 768 + mat * 256 + d0];
    if (mat == 0)      *(bf16x8*)&Qs[r][d0] = v8;
    else if (mat == 1) *(bf16x8*)&Ks[r][d0] = v8;
    else {
#pragma unroll
      for (int e = 0; e < 8; ++e) Vt[d0 + e][r] = v8[e];
    }
  }
  __syncthreads();
  const int wave = tid >> 6, lane = tid & 63;
  const int fr = lane & 15, g = lane >> 4;
  const int q0 = wave * 16;
  const float wd = Wdep[h], bd = bdep[h];
  float depb[6];
#pragma unroll
  for (int f = 0; f < 6; ++f) depb[f] = depm[slab + fr + 16 * f] * wd + bd;
  const bf16x8 av = *(const bf16x8*)&Qs[q0 + fr][g * 8];
  f32x4 sacc[6];
#pragma unroll
  for (int f = 0; f < 6; ++f) {
    const bf16x8 bv = *(const bf16x8*)&Ks[f * 16 + fr][g * 8];
    sacc[f] = __builtin_amdgcn_mfma_f32_16x16x32_bf16(av, bv, (f32x4){0.f, 0.f, 0.f, 0.f}, 0, 0, 0);
  }
  const float scale = 0.17677669529663687f;
  float ev[6][4];
  float inv[4];
#pragma unroll
  for (int r = 0; r < 4; ++r) {
    float m = -1e30f;
#pragma unroll
    for (int f = 0; f < 6; ++f) {
      ev[f][r] = sacc[f][r] * scale + depb[f];
      m = fmaxf(m, ev[f][r]);
    }
#pragma unroll
    for (int o = 8; o > 0; o >>= 1) m = fmaxf(m, __shfl_xor(m, o));
    float sum = 0.f;
#pragma unroll
    for (int f = 0; f < 6; ++f) { ev[f][r] = __expf(ev[f][r] - m); sum += ev[f][r]; }
#pragma unroll
    for (int o = 8; o > 0; o >>= 1) sum += __shfl_xor(sum, o);
    inv[r] = 1.0f / sum;
  }
#pragma unroll
  for (int f = 0; f < 6; ++f)
#pragma unroll
    for (int r = 0; r < 4; ++r)
      Ps[wave][g * 4 + r][fr + 16 * f] = (__bf16)ev[f][r];
  asm volatile("s_waitcnt lgkmcnt(0)" ::: "memory");
  f32x4 o0 = {0.f, 0.f, 0.f, 0.f}, o1 = {0.f, 0.f, 0.f, 0.f};
#pragma unroll
  for (int s = 0; s < 3; ++s) {
    const bf16x8 pa  = *(const bf16x8*)&Ps[wave][fr][s * 32 + g * 8];
    const bf16x8 vb0 = *(const bf16x8*)&Vt[fr][s * 32 + g * 8];
    const bf16x8 vb1 = *(const bf16x8*)&Vt[16 + fr][s * 32 + g * 8];
    o0 = __builtin_amdgcn_mfma_f32_16x16x32_bf16(pa, vb0, o0, 0, 0, 0);
    o1 = __builtin_amdgcn_mfma_f32_16x16x32_bf16(pa, vb1, o1, 0, 0, 0);
  }
  const size_t orow = (slab + q0 + g * 4) * 256 + h * 32;
#pragma unroll
  for (int r = 0; r < 4; ++r) {
    ctx[orow + (size_t)r * 256 + fr]      = __float2bfloat16(o0[r] * inv[r]);
    ctx[orow + (size_t)r * 256 + 16 + fr] = __float2bfloat16(o1[r] * inv[r]);
  }
}

extern "C" void kernel_launch(void* const* d_in, const int* in_sizes, int n_in,
                              void* d_out, int out_size, void* d_ws, size_t ws_size,
                              hipStream_t stream) {
  (void)in_sizes; (void)n_in; (void)out_size; (void)ws_size;
  const float* table = (const float*)d_in[0];
  const float* depm  = (const float*)d_in[1];
  const float* Wq = (const float*)d_in[2];   const float* bq = (const float*)d_in[3];
  const float* Wk = (const float*)d_in[4];   const float* bk = (const float*)d_in[5];
  const float* Wv = (const float*)d_in[6];   const float* bv = (const float*)d_in[7];
  const float* Wo = (const float*)d_in[8];   const float* bo = (const float*)d_in[9];
  const float* Wdep = (const float*)d_in[10]; const float* bdep = (const float*)d_in[11];
  const float* g1 = (const float*)d_in[12];  const float* be1 = (const float*)d_in[13];
  const float* W1 = (const float*)d_in[14];  const float* b1 = (const float*)d_in[15];
  const float* W2 = (const float*)d_in[16];  const float* b2 = (const float*)d_in[17];
  const float* g2 = (const float*)d_in[18];  const float* be2 = (const float*)d_in[19];

  char* ws = (char*)d_ws;
  size_t off = 0;
  __bf16* qkvb  = (__bf16*)(ws + off); off += (size_t)M_ROWS * 768 * 2;
  __bf16* ctxb  = (__bf16*)(ws + off); off += (size_t)M_ROWS * 256 * 2;
  float*  outb  = (float*) (ws + off); off += (size_t)M_ROWS * 256 * 4;
  __bf16* outbb = (__bf16*)(ws + off); off += (size_t)M_ROWS * 256 * 2;
  __bf16* hidb  = (__bf16*)(ws + off); off += (size_t)M_ROWS * 1024 * 2;
  __bf16* tabb  = (__bf16*)(ws + off); off += (size_t)M_ROWS * 256 * 2;
  __bf16* Wqkv_t = (__bf16*)(ws + off); off += 768 * 256 * 2;
  __bf16* Wo_t   = (__bf16*)(ws + off); off += 256 * 256 * 2;
  __bf16* W1_t   = (__bf16*)(ws + off); off += 1024 * 256 * 2;
  __bf16* W2_t   = (__bf16*)(ws + off); off += 256 * 1024 * 2;
  float*  bqkv   = (float*)(ws + off);

  cvt_bf16_kernel<<<4608, 256, 0, stream>>>(table, tabb, M_ROWS * 256 / 8);
  pack_w_kernel<<<3072, 256, 0, stream>>>(Wq, Wk, Wv, Wo, W1, W2, bq, bk, bv,
                                          Wqkv_t, Wo_t, W1_t, W2_t, bqkv);
  // qkv = table @ Wqkv + bqkv -> bf16 [M,768]
  gemm8_kernel<0, false><<<dim3(3, 288), 512, 0, stream>>>(
      tabb, Wqkv_t, bqkv, nullptr, nullptr, nullptr, qkvb, nullptr, 768, 256);
  // attention -> ctx bf16 [M,256]
  attn_mfma_kernel<<<3072, 384, 0, stream>>>(qkvb, depm, Wdep, bdep, (__hip_bfloat16*)ctxb);
  // outb/outbb = LN1(ctx @ Wo + bo + table)  [fused]
  gemm8_kernel<2, true><<<dim3(1, 288), 512, 0, stream>>>(
      ctxb, Wo_t, bo, table, g1, be1, outb, (__hip_bfloat16*)outbb, 256, 256);
  // hidden = relu(outbb @ W1 + b1) -> bf16 [M,1024]
  gemm8_kernel<1, false><<<dim3(4, 288), 512, 0, stream>>>(
      outbb, W1_t, b1, nullptr, nullptr, nullptr, hidb, nullptr, 1024, 256);
  // d_out = LN2(hidden @ W2 + b2 + outb)  [fused]
  gemm8_kernel<2, false><<<dim3(1, 288), 512, 0, stream>>>(
      hidb, W2_t, b2, outb, g2, be2, (float*)d_out, nullptr, 256, 1024);
}

// Round 8
// 195.485 us; speedup vs baseline: 1.2370x; 1.2370x over previous
//
#include <hip/hip_runtime.h>
#include <hip/hip_bf16.h>
#include <math.h>

// Problem constants: B=4, L=96, D=256, H=8, hd=32, FF=1024. M = B*L*L = 36864.
#define M_ROWS 36864

typedef __bf16 bf16x8 __attribute__((ext_vector_type(8)));
typedef __bf16 bf16x4 __attribute__((ext_vector_type(4)));
typedef float f32x4 __attribute__((ext_vector_type(4)));

__device__ __forceinline__ void gload16(const void* g, void* l) {
  __builtin_amdgcn_global_load_lds((const __attribute__((address_space(1))) void*)g,
                                   (__attribute__((address_space(3))) void*)l, 16, 0, 0);
}

// ---------------- convert table fp32 -> bf16 (8 elems/thread) ----------------
__global__ __launch_bounds__(256) void cvt_bf16_kernel(const float* __restrict__ X,
                                                       __bf16* __restrict__ Y, int n8) {
  int i = blockIdx.x * 256 + threadIdx.x;
  if (i >= n8) return;
  const float4 a = ((const float4*)X)[(size_t)i * 2];
  const float4 b = ((const float4*)X)[(size_t)i * 2 + 1];
  bf16x8 o = {(__bf16)a.x, (__bf16)a.y, (__bf16)a.z, (__bf16)a.w,
              (__bf16)b.x, (__bf16)b.y, (__bf16)b.z, (__bf16)b.w};
  *(bf16x8*)&Y[(size_t)i * 8] = o;
}

// ---------------- pack + transpose weights to bf16 B^T [N,K] ----------------
__global__ __launch_bounds__(256) void pack_w_kernel(
    const float* __restrict__ Wq, const float* __restrict__ Wk, const float* __restrict__ Wv,
    const float* __restrict__ Wo, const float* __restrict__ W1, const float* __restrict__ W2,
    const float* __restrict__ bq, const float* __restrict__ bk, const float* __restrict__ bv,
    __bf16* __restrict__ Wqkv_t, __bf16* __restrict__ Wo_t,
    __bf16* __restrict__ W1_t, __bf16* __restrict__ W2_t, float* __restrict__ bqkv) {
  int idx = blockIdx.x * 256 + threadIdx.x;
  const int S1 = 768 * 256, S2 = 256 * 256, S3 = 1024 * 256;
  if (idx < S1) {
    int n = idx / 256, k = idx % 256;
    int sel = n >> 8, nn = n & 255;
    const float* W = (sel == 0) ? Wq : (sel == 1) ? Wk : Wv;
    Wqkv_t[idx] = (__bf16)W[k * 256 + nn];
  } else if (idx < S1 + S2) {
    int j = idx - S1; int n = j / 256, k = j % 256;
    Wo_t[j] = (__bf16)Wo[k * 256 + n];
  } else if (idx < S1 + S2 + S3) {
    int j = idx - S1 - S2; int n = j / 256, k = j % 256;
    W1_t[j] = (__bf16)W1[k * 1024 + n];
  } else {
    int j = idx - S1 - S2 - S3; int n = j / 1024, k = j % 1024;
    W2_t[j] = (__bf16)W2[k * 256 + n];
  }
  if (idx < 768) {
    int sel = idx >> 8, jj = idx & 255;
    const float* bsrc = (sel == 0) ? bq : (sel == 1) ? bk : bv;
    bqkv[idx] = bsrc[jj];
  }
}

// -------- small-tile MFMA GEMM: BM=64 x BN=128, BK=32, 4 waves, 24KB LDS ------
// Many blocks/CU -> TLP/MLP does the latency hiding (m97 regime).
// Wave grid 2m x 2n; per-wave 32x64 = 2x4 frags of 16x16x32.
// EPI: 0 = bias -> bf16, 1 = bias+relu -> bf16, 2 = bias + bf16 resid -> bf16.
template <int EPI>
__global__ __launch_bounds__(256, 4) void gemm_small_kernel(
    const __bf16* __restrict__ A, const __bf16* __restrict__ Bt,
    const float* __restrict__ bias, const __bf16* __restrict__ resid,
    __hip_bfloat16* __restrict__ Y, int N, int K) {
  __shared__ __bf16 As[2][64 * 32];
  __shared__ __bf16 Bs[2][128 * 32];
  const int tid = threadIdx.x;
  const int lane = tid & 63, wv = tid >> 6;
  const int wm = wv >> 1, wn = wv & 1;
  // XCD-chunked swizzle, n-fastest within chunk (A-panel L2 reuse)
  const int gx = gridDim.x;
  const int nwg = gx * gridDim.y;
  int lin = blockIdx.y * gx + blockIdx.x;
  lin = (lin & 7) * (nwg >> 3) + (lin >> 3);
  const int n0 = (lin % gx) * 128;
  const int m0 = (lin / gx) * 64;
  const int fr = lane & 15, g = lane >> 4;
  const int rrel = lane >> 2;                                // 0..15 within wave
  const int gsegA = ((lane & 3) ^ ((lane >> 3) & 3)) * 8;    // pre-swizzled src colseg

  f32x4 acc[2][4] = {};
  const int nph = K >> 5;

#define STAGE_S(buf, kb)                                                        \
  {                                                                             \
    gload16(A + (size_t)(m0 + wv * 16 + rrel) * K + (kb) + gsegA,               \
            &As[buf][wv * 512]);                                                \
    gload16(Bt + (size_t)(n0 + wv * 16 + rrel) * K + (kb) + gsegA,              \
            &Bs[buf][wv * 512]);                                                \
    gload16(Bt + (size_t)(n0 + 64 + wv * 16 + rrel) * K + (kb) + gsegA,         \
            &Bs[buf][2048 + wv * 512]);                                         \
  }

  STAGE_S(0, 0)
  __syncthreads();
  int cur = 0;
  for (int p = 0; p < nph; ++p) {
    if (p + 1 < nph) STAGE_S(cur ^ 1, (p + 1) * 32)
    const int cs = (g ^ ((fr >> 1) & 3)) * 8;   // read-side un-swizzle
    bf16x8 av[2], bv[4];
#pragma unroll
    for (int mi = 0; mi < 2; ++mi)
      av[mi] = *reinterpret_cast<const bf16x8*>(&As[cur][(wm * 32 + mi * 16 + fr) * 32 + cs]);
#pragma unroll
    for (int ni = 0; ni < 4; ++ni)
      bv[ni] = *reinterpret_cast<const bf16x8*>(&Bs[cur][(wn * 64 + ni * 16 + fr) * 32 + cs]);
#pragma unroll
    for (int mi = 0; mi < 2; ++mi)
#pragma unroll
      for (int ni = 0; ni < 4; ++ni)
        acc[mi][ni] = __builtin_amdgcn_mfma_f32_16x16x32_bf16(av[mi], bv[ni], acc[mi][ni], 0, 0, 0);
    __syncthreads();
    cur ^= 1;
  }
#undef STAGE_S

  // epilogue: C/D layout col=lane&15, row=(lane>>4)*4+reg
  const int crow = m0 + wm * 32 + g * 4;
  const int ccol = n0 + wn * 64 + fr;
#pragma unroll
  for (int mi = 0; mi < 2; ++mi) {
#pragma unroll
    for (int ni = 0; ni < 4; ++ni) {
      const int col = ccol + ni * 16;
      const float bb = bias[col];
#pragma unroll
      for (int r = 0; r < 4; ++r) {
        const int row = crow + mi * 16 + r;
        float v = acc[mi][ni][r] + bb;
        if (EPI == 1) v = fmaxf(v, 0.f);
        if (EPI == 2) v += (float)resid[(size_t)row * N + col];
        Y[(size_t)row * N + col] = __float2bfloat16(v);
      }
    }
  }
}

// ---------------- LayerNorm over last dim 256, bf16 in; wave per row ----------
template <bool F32OUT>
__global__ __launch_bounds__(256) void ln_bf16_kernel(const __bf16* __restrict__ X,
                                                      const float* __restrict__ gam,
                                                      const float* __restrict__ bet,
                                                      void* __restrict__ Yv) {
  const int row = blockIdx.x * 4 + (threadIdx.x >> 6);
  const int lane = threadIdx.x & 63;
  const size_t base = (size_t)row * 256 + lane * 4;
  bf16x4 x4 = *(const bf16x4*)&X[base];
  float xs[4] = {(float)x4[0], (float)x4[1], (float)x4[2], (float)x4[3]};
  float s = xs[0] + xs[1] + xs[2] + xs[3];
  float q = xs[0] * xs[0] + xs[1] * xs[1] + xs[2] * xs[2] + xs[3] * xs[3];
#pragma unroll
  for (int o = 32; o > 0; o >>= 1) { s += __shfl_xor(s, o); q += __shfl_xor(q, o); }
  const float mean = s * (1.0f / 256.0f);
  const float var = q * (1.0f / 256.0f) - mean * mean;
  const float inv = rsqrtf(var + 1e-5f);
  float4 g4 = *(const float4*)&gam[lane * 4];
  float4 b4 = *(const float4*)&bet[lane * 4];
  float gg[4] = {g4.x, g4.y, g4.z, g4.w};
  float bb[4] = {b4.x, b4.y, b4.z, b4.w};
  if (F32OUT) {
    float4 y4;
    float* yp = &y4.x;
#pragma unroll
    for (int j = 0; j < 4; ++j) yp[j] = (xs[j] - mean) * inv * gg[j] + bb[j];
    *(float4*)&((float*)Yv)[base] = y4;
  } else {
    bf16x4 y4;
#pragma unroll
    for (int j = 0; j < 4; ++j) y4[j] = (__bf16)((xs[j] - mean) * inv * gg[j] + bb[j]);
    *(bf16x4*)&((__bf16*)Yv)[base] = y4;
  }
}

// ---------------- MFMA attention: one block per (b,h,x), 6 waves ----------------
__global__ __launch_bounds__(384) void attn_mfma_kernel(
    const __bf16* __restrict__ qkv, const float* __restrict__ depm,
    const float* __restrict__ Wdep, const float* __restrict__ bdep,
    __hip_bfloat16* __restrict__ ctx) {
  __shared__ __bf16 Qs[96][40];
  __shared__ __bf16 Ks[96][40];
  __shared__ __bf16 Vt[32][104];
  __shared__ __bf16 Ps[6][16][104];
  // XCD swizzle: 8 heads of one (b,x) slab -> consecutive -> same XCD L2
  int lin = blockIdx.x;
  lin = (lin & 7) * 384 + (lin >> 3);
  const int h = lin & 7;
  const int sx = lin >> 3;
  const int x = sx % 96;
  const int b = sx / 96;
  const int tid = threadIdx.x;
  const size_t slab = (size_t)(b * 96 + x) * 96;
  const size_t base = slab * 768 + h * 32;
#pragma unroll
  for (int t = 0; t < 3; ++t) {
    const int idx = tid + t * 384;
    const int r = idx / 12, rem = idx % 12, mat = rem >> 2, seg = rem & 3;
    const int d0 = seg * 8;
    bf16x8 v8 = *(const bf16x8*)&qkv[base + (size_t)r * 768 + mat * 256 + d0];
    if (mat == 0)      *(bf16x8*)&Qs[r][d0] = v8;
    else if (mat == 1) *(bf16x8*)&Ks[r][d0] = v8;
    else {
#pragma unroll
      for (int e = 0; e < 8; ++e) Vt[d0 + e][r] = v8[e];
    }
  }
  __syncthreads();
  const int wave = tid >> 6, lane = tid & 63;
  const int fr = lane & 15, g = lane >> 4;
  const int q0 = wave * 16;
  const float wd = Wdep[h], bd = bdep[h];
  float depb[6];
#pragma unroll
  for (int f = 0; f < 6; ++f) depb[f] = depm[slab + fr + 16 * f] * wd + bd;
  const bf16x8 av = *(const bf16x8*)&Qs[q0 + fr][g * 8];
  f32x4 sacc[6];
#pragma unroll
  for (int f = 0; f < 6; ++f) {
    const bf16x8 bv = *(const bf16x8*)&Ks[f * 16 + fr][g * 8];
    sacc[f] = __builtin_amdgcn_mfma_f32_16x16x32_bf16(av, bv, (f32x4){0.f, 0.f, 0.f, 0.f}, 0, 0, 0);
  }
  const float scale = 0.17677669529663687f;
  float ev[6][4];
  float inv[4];
#pragma unroll
  for (int r = 0; r < 4; ++r) {
    float m = -1e30f;
#pragma unroll
    for (int f = 0; f < 6; ++f) {
      ev[f][r] = sacc[f][r] * scale + depb[f];
      m = fmaxf(m, ev[f][r]);
    }
#pragma unroll
    for (int o = 8; o > 0; o >>= 1) m = fmaxf(m, __shfl_xor(m, o));
    float sum = 0.f;
#pragma unroll
    for (int f = 0; f < 6; ++f) { ev[f][r] = __expf(ev[f][r] - m); sum += ev[f][r]; }
#pragma unroll
    for (int o = 8; o > 0; o >>= 1) sum += __shfl_xor(sum, o);
    inv[r] = 1.0f / sum;
  }
#pragma unroll
  for (int f = 0; f < 6; ++f)
#pragma unroll
    for (int r = 0; r < 4; ++r)
      Ps[wave][g * 4 + r][fr + 16 * f] = (__bf16)ev[f][r];
  asm volatile("s_waitcnt lgkmcnt(0)" ::: "memory");
  f32x4 o0 = {0.f, 0.f, 0.f, 0.f}, o1 = {0.f, 0.f, 0.f, 0.f};
#pragma unroll
  for (int s = 0; s < 3; ++s) {
    const bf16x8 pa  = *(const bf16x8*)&Ps[wave][fr][s * 32 + g * 8];
    const bf16x8 vb0 = *(const bf16x8*)&Vt[fr][s * 32 + g * 8];
    const bf16x8 vb1 = *(const bf16x8*)&Vt[16 + fr][s * 32 + g * 8];
    o0 = __builtin_amdgcn_mfma_f32_16x16x32_bf16(pa, vb0, o0, 0, 0, 0);
    o1 = __builtin_amdgcn_mfma_f32_16x16x32_bf16(pa, vb1, o1, 0, 0, 0);
  }
  const size_t orow = (slab + q0 + g * 4) * 256 + h * 32;
#pragma unroll
  for (int r = 0; r < 4; ++r) {
    ctx[orow + (size_t)r * 256 + fr]      = __float2bfloat16(o0[r] * inv[r]);
    ctx[orow + (size_t)r * 256 + 16 + fr] = __float2bfloat16(o1[r] * inv[r]);
  }
}

extern "C" void kernel_launch(void* const* d_in, const int* in_sizes, int n_in,
                              void* d_out, int out_size, void* d_ws, size_t ws_size,
                              hipStream_t stream) {
  (void)in_sizes; (void)n_in; (void)out_size; (void)ws_size;
  const float* table = (const float*)d_in[0];
  const float* depm  = (const float*)d_in[1];
  const float* Wq = (const float*)d_in[2];   const float* bq = (const float*)d_in[3];
  const float* Wk = (const float*)d_in[4];   const float* bk = (const float*)d_in[5];
  const float* Wv = (const float*)d_in[6];   const float* bv = (const float*)d_in[7];
  const float* Wo = (const float*)d_in[8];   const float* bo = (const float*)d_in[9];
  const float* Wdep = (const float*)d_in[10]; const float* bdep = (const float*)d_in[11];
  const float* g1 = (const float*)d_in[12];  const float* be1 = (const float*)d_in[13];
  const float* W1 = (const float*)d_in[14];  const float* b1 = (const float*)d_in[15];
  const float* W2 = (const float*)d_in[16];  const float* b2 = (const float*)d_in[17];
  const float* g2 = (const float*)d_in[18];  const float* be2 = (const float*)d_in[19];

  char* ws = (char*)d_ws;
  size_t off = 0;
  __bf16* qkvb  = (__bf16*)(ws + off); off += (size_t)M_ROWS * 768 * 2;   // 56.6MB
  __bf16* ctxb  = (__bf16*)(ws + off); off += (size_t)M_ROWS * 256 * 2;   // 18.9MB
  __bf16* pre1b = (__bf16*)(ws + off); off += (size_t)M_ROWS * 256 * 2;   // 18.9MB
  __bf16* outbb = (__bf16*)(ws + off); off += (size_t)M_ROWS * 256 * 2;   // 18.9MB
  __bf16* hidb  = (__bf16*)(ws + off); off += (size_t)M_ROWS * 1024 * 2;  // 75.5MB
  __bf16* pre2b = (__bf16*)(ws + off); off += (size_t)M_ROWS * 256 * 2;   // 18.9MB
  __bf16* tabb  = (__bf16*)(ws + off); off += (size_t)M_ROWS * 256 * 2;   // 18.9MB
  __bf16* Wqkv_t = (__bf16*)(ws + off); off += 768 * 256 * 2;
  __bf16* Wo_t   = (__bf16*)(ws + off); off += 256 * 256 * 2;
  __bf16* W1_t   = (__bf16*)(ws + off); off += 1024 * 256 * 2;
  __bf16* W2_t   = (__bf16*)(ws + off); off += 256 * 1024 * 2;
  float*  bqkv   = (float*)(ws + off);

  cvt_bf16_kernel<<<4608, 256, 0, stream>>>(table, tabb, M_ROWS * 256 / 8);
  pack_w_kernel<<<3072, 256, 0, stream>>>(Wq, Wk, Wv, Wo, W1, W2, bq, bk, bv,
                                          Wqkv_t, Wo_t, W1_t, W2_t, bqkv);
  // qkv = table @ Wqkv + bqkv -> bf16 [M,768]
  gemm_small_kernel<0><<<dim3(6, 576), 256, 0, stream>>>(
      tabb, Wqkv_t, bqkv, nullptr, (__hip_bfloat16*)qkvb, 768, 256);
  // attention -> ctx bf16 [M,256]
  attn_mfma_kernel<<<3072, 384, 0, stream>>>(qkvb, depm, Wdep, bdep, (__hip_bfloat16*)ctxb);
  // pre1 = ctx @ Wo + bo + table(bf16 resid)
  gemm_small_kernel<2><<<dim3(2, 576), 256, 0, stream>>>(
      ctxb, Wo_t, bo, tabb, (__hip_bfloat16*)pre1b, 256, 256);
  // outbb = LN1(pre1) (bf16)
  ln_bf16_kernel<false><<<9216, 256, 0, stream>>>(pre1b, g1, be1, outbb);
  // hidden = relu(outbb @ W1 + b1) -> bf16 [M,1024]
  gemm_small_kernel<1><<<dim3(8, 576), 256, 0, stream>>>(
      outbb, W1_t, b1, nullptr, (__hip_bfloat16*)hidb, 1024, 256);
  // pre2 = hidden @ W2 + b2 + outbb(resid)
  gemm_small_kernel<2><<<dim3(2, 576), 256, 0, stream>>>(
      hidb, W2_t, b2, outbb, (__hip_bfloat16*)pre2b, 256, 1024);
  // d_out = LN2(pre2) fp32
  ln_bf16_kernel<true><<<9216, 256, 0, stream>>>(pre2b, g2, be2, (float*)d_out);
}

// Round 9
// 182.655 us; speedup vs baseline: 1.3239x; 1.0702x over previous
//
#include <hip/hip_runtime.h>
#include <hip/hip_bf16.h>
#include <math.h>

// Problem constants: B=4, L=96, D=256, H=8, hd=32, FF=1024. M = B*L*L = 36864.
#define M_ROWS 36864

typedef __bf16 bf16x8 __attribute__((ext_vector_type(8)));
typedef __bf16 bf16x4 __attribute__((ext_vector_type(4)));
typedef float f32x4 __attribute__((ext_vector_type(4)));

__device__ __forceinline__ void gload16(const void* g, void* l) {
  __builtin_amdgcn_global_load_lds((const __attribute__((address_space(1))) void*)g,
                                   (__attribute__((address_space(3))) void*)l, 16, 0, 0);
}

// ---------------- convert table fp32 -> bf16 (8 elems/thread) ----------------
__global__ __launch_bounds__(256) void cvt_bf16_kernel(const float* __restrict__ X,
                                                       __bf16* __restrict__ Y, int n8) {
  int i = blockIdx.x * 256 + threadIdx.x;
  if (i >= n8) return;
  const float4 a = ((const float4*)X)[(size_t)i * 2];
  const float4 b = ((const float4*)X)[(size_t)i * 2 + 1];
  bf16x8 o = {(__bf16)a.x, (__bf16)a.y, (__bf16)a.z, (__bf16)a.w,
              (__bf16)b.x, (__bf16)b.y, (__bf16)b.z, (__bf16)b.w};
  *(bf16x8*)&Y[(size_t)i * 8] = o;
}

// ---------------- pack + transpose weights to bf16 B^T [N,K] ----------------
__global__ __launch_bounds__(256) void pack_w_kernel(
    const float* __restrict__ Wq, const float* __restrict__ Wk, const float* __restrict__ Wv,
    const float* __restrict__ Wo, const float* __restrict__ W1, const float* __restrict__ W2,
    const float* __restrict__ bq, const float* __restrict__ bk, const float* __restrict__ bv,
    __bf16* __restrict__ Wqkv_t, __bf16* __restrict__ Wo_t,
    __bf16* __restrict__ W1_t, __bf16* __restrict__ W2_t, float* __restrict__ bqkv) {
  int idx = blockIdx.x * 256 + threadIdx.x;
  const int S1 = 768 * 256, S2 = 256 * 256, S3 = 1024 * 256;
  if (idx < S1) {
    int n = idx / 256, k = idx % 256;
    int sel = n >> 8, nn = n & 255;
    const float* W = (sel == 0) ? Wq : (sel == 1) ? Wk : Wv;
    Wqkv_t[idx] = (__bf16)W[k * 256 + nn];
  } else if (idx < S1 + S2) {
    int j = idx - S1; int n = j / 256, k = j % 256;
    Wo_t[j] = (__bf16)Wo[k * 256 + n];
  } else if (idx < S1 + S2 + S3) {
    int j = idx - S1 - S2; int n = j / 256, k = j % 256;
    W1_t[j] = (__bf16)W1[k * 1024 + n];
  } else {
    int j = idx - S1 - S2 - S3; int n = j / 1024, k = j % 1024;
    W2_t[j] = (__bf16)W2[k * 256 + n];
  }
  if (idx < 768) {
    int sel = idx >> 8, jj = idx & 255;
    const float* bsrc = (sel == 0) ? bq : (sel == 1) ? bk : bv;
    bqkv[idx] = bsrc[jj];
  }
}

// -------- MFMA GEMM: BM=64 x BN=128, BK=64, 4 waves, 24KB LDS, m97-style ------
// Many blocks/CU (launch_bounds(256,4) -> 4 blocks/CU): TLP hides the staging.
// Per phase: stage 6x gload16, sync, 2 k-slices x (6 ds_read_b128 + 8 MFMA).
// Swizzle: src granule (lane&7)^((lane>>3)&7), read granule (s*4+g)^(fr&7) -> 2-way (free).
// EPI: 0 = bias -> bf16, 1 = bias+relu -> bf16, 2 = bias + bf16 resid -> bf16.
template <int EPI>
__global__ __launch_bounds__(256, 4) void gemm_k64_kernel(
    const __bf16* __restrict__ A, const __bf16* __restrict__ Bt,
    const float* __restrict__ bias, const __bf16* __restrict__ resid,
    __hip_bfloat16* __restrict__ Y, int N, int K) {
  __shared__ __bf16 As[64 * 64];    // 8KB
  __shared__ __bf16 Bs[128 * 64];   // 16KB
  const int tid = threadIdx.x;
  const int lane = tid & 63, wv = tid >> 6;
  const int wm = wv >> 1, wn = wv & 1;
  // XCD-chunked swizzle, n-fastest within chunk (A-panel L2 reuse)
  const int gx = gridDim.x;
  const int nwg = gx * gridDim.y;
  int lin = blockIdx.y * gx + blockIdx.x;
  lin = (lin & 7) * (nwg >> 3) + (lin >> 3);
  const int n0 = (lin % gx) * 128;
  const int m0 = (lin / gx) * 64;
  const int fr = lane & 15, g = lane >> 4;
  const int lrow8 = lane >> 3;                               // 0..7 (row within 8-row chunk)
  const int gseg = ((lane & 7) ^ ((lane >> 3) & 7)) * 8;     // pre-swizzled src col (elems)

  f32x4 acc[2][4] = {};
  const int nph = K >> 6;

  for (int p = 0; p < nph; ++p) {
    const int kb = p * 64;
    __syncthreads();   // all waves done reading previous phase's LDS
    // A: 64 rows = 8 chunks of 8 rows; wave stages chunks wv*2, wv*2+1
    gload16(A + (size_t)(m0 + wv * 16 + lrow8) * K + kb + gseg,       &As[wv * 1024]);
    gload16(A + (size_t)(m0 + wv * 16 + 8 + lrow8) * K + kb + gseg,   &As[wv * 1024 + 512]);
    // B: 128 rows = 16 chunks; wave stages chunks wv*4 .. wv*4+3
#pragma unroll
    for (int j = 0; j < 4; ++j)
      gload16(Bt + (size_t)(n0 + wv * 32 + j * 8 + lrow8) * K + kb + gseg,
              &Bs[wv * 2048 + j * 512]);
    __syncthreads();   // implicit vmcnt(0): staged data visible
#pragma unroll
    for (int s = 0; s < 2; ++s) {
      bf16x8 av[2], bv[4];
#pragma unroll
      for (int mi = 0; mi < 2; ++mi) {
        const int row = wm * 32 + mi * 16 + fr;
        av[mi] = *reinterpret_cast<const bf16x8*>(&As[row * 64 + (((s * 4 + g) ^ (fr & 7)) * 8)]);
      }
#pragma unroll
      for (int ni = 0; ni < 4; ++ni) {
        const int row = wn * 64 + ni * 16 + fr;
        bv[ni] = *reinterpret_cast<const bf16x8*>(&Bs[row * 64 + (((s * 4 + g) ^ (fr & 7)) * 8)]);
      }
#pragma unroll
      for (int mi = 0; mi < 2; ++mi)
#pragma unroll
        for (int ni = 0; ni < 4; ++ni)
          acc[mi][ni] = __builtin_amdgcn_mfma_f32_16x16x32_bf16(av[mi], bv[ni], acc[mi][ni], 0, 0, 0);
    }
  }

  // epilogue: C/D layout col=lane&15, row=(lane>>4)*4+reg
  const int crow = m0 + wm * 32 + g * 4;
  const int ccol = n0 + wn * 64 + fr;
#pragma unroll
  for (int mi = 0; mi < 2; ++mi) {
#pragma unroll
    for (int ni = 0; ni < 4; ++ni) {
      const int col = ccol + ni * 16;
      const float bb = bias[col];
#pragma unroll
      for (int r = 0; r < 4; ++r) {
        const int row = crow + mi * 16 + r;
        float v = acc[mi][ni][r] + bb;
        if (EPI == 1) v = fmaxf(v, 0.f);
        if (EPI == 2) v += (float)resid[(size_t)row * N + col];
        Y[(size_t)row * N + col] = __float2bfloat16(v);
      }
    }
  }
}

// ---------------- LayerNorm over last dim 256, bf16 in; wave per row ----------
template <bool F32OUT>
__global__ __launch_bounds__(256) void ln_bf16_kernel(const __bf16* __restrict__ X,
                                                      const float* __restrict__ gam,
                                                      const float* __restrict__ bet,
                                                      void* __restrict__ Yv) {
  const int row = blockIdx.x * 4 + (threadIdx.x >> 6);
  const int lane = threadIdx.x & 63;
  const size_t base = (size_t)row * 256 + lane * 4;
  bf16x4 x4 = *(const bf16x4*)&X[base];
  float xs[4] = {(float)x4[0], (float)x4[1], (float)x4[2], (float)x4[3]};
  float s = xs[0] + xs[1] + xs[2] + xs[3];
  float q = xs[0] * xs[0] + xs[1] * xs[1] + xs[2] * xs[2] + xs[3] * xs[3];
#pragma unroll
  for (int o = 32; o > 0; o >>= 1) { s += __shfl_xor(s, o); q += __shfl_xor(q, o); }
  const float mean = s * (1.0f / 256.0f);
  const float var = q * (1.0f / 256.0f) - mean * mean;
  const float inv = rsqrtf(var + 1e-5f);
  float4 g4 = *(const float4*)&gam[lane * 4];
  float4 b4 = *(const float4*)&bet[lane * 4];
  float gg[4] = {g4.x, g4.y, g4.z, g4.w};
  float bb[4] = {b4.x, b4.y, b4.z, b4.w};
  if (F32OUT) {
    float4 y4;
    float* yp = &y4.x;
#pragma unroll
    for (int j = 0; j < 4; ++j) yp[j] = (xs[j] - mean) * inv * gg[j] + bb[j];
    *(float4*)&((float*)Yv)[base] = y4;
  } else {
    bf16x4 y4;
#pragma unroll
    for (int j = 0; j < 4; ++j) y4[j] = (__bf16)((xs[j] - mean) * inv * gg[j] + bb[j]);
    *(bf16x4*)&((__bf16*)Yv)[base] = y4;
  }
}

// ---------------- MFMA attention: one block per (b,h,x), 6 waves ----------------
__global__ __launch_bounds__(384) void attn_mfma_kernel(
    const __bf16* __restrict__ qkv, const float* __restrict__ depm,
    const float* __restrict__ Wdep, const float* __restrict__ bdep,
    __hip_bfloat16* __restrict__ ctx) {
  __shared__ __bf16 Qs[96][40];
  __shared__ __bf16 Ks[96][40];
  __shared__ __bf16 Vt[32][104];
  __shared__ __bf16 Ps[6][16][104];
  // XCD swizzle: 8 heads of one (b,x) slab -> consecutive -> same XCD L2
  int lin = blockIdx.x;
  lin = (lin & 7) * 384 + (lin >> 3);
  const int h = lin & 7;
  const int sx = lin >> 3;
  const int x = sx % 96;
  const int b = sx / 96;
  const int tid = threadIdx.x;
  const size_t slab = (size_t)(b * 96 + x) * 96;
  const size_t base = slab * 768 + h * 32;
#pragma unroll
  for (int t = 0; t < 3; ++t) {
    const int idx = tid + t * 384;
    const int r = idx / 12, rem = idx % 12, mat = rem >> 2, seg = rem & 3;
    const int d0 = seg * 8;
    bf16x8 v8 = *(const bf16x8*)&qkv[base + (size_t)r * 768 + mat * 256 + d0];
    if (mat == 0)      *(bf16x8*)&Qs[r][d0] = v8;
    else if (mat == 1) *(bf16x8*)&Ks[r][d0] = v8;
    else {
#pragma unroll
      for (int e = 0; e < 8; ++e) Vt[d0 + e][r] = v8[e];
    }
  }
  __syncthreads();
  const int wave = tid >> 6, lane = tid & 63;
  const int fr = lane & 15, g = lane >> 4;
  const int q0 = wave * 16;
  const float wd = Wdep[h], bd = bdep[h];
  float depb[6];
#pragma unroll
  for (int f = 0; f < 6; ++f) depb[f] = depm[slab + fr + 16 * f] * wd + bd;
  const bf16x8 av = *(const bf16x8*)&Qs[q0 + fr][g * 8];
  f32x4 sacc[6];
#pragma unroll
  for (int f = 0; f < 6; ++f) {
    const bf16x8 bv = *(const bf16x8*)&Ks[f * 16 + fr][g * 8];
    sacc[f] = __builtin_amdgcn_mfma_f32_16x16x32_bf16(av, bv, (f32x4){0.f, 0.f, 0.f, 0.f}, 0, 0, 0);
  }
  const float scale = 0.17677669529663687f;
  float ev[6][4];
  float inv[4];
#pragma unroll
  for (int r = 0; r < 4; ++r) {
    float m = -1e30f;
#pragma unroll
    for (int f = 0; f < 6; ++f) {
      ev[f][r] = sacc[f][r] * scale + depb[f];
      m = fmaxf(m, ev[f][r]);
    }
#pragma unroll
    for (int o = 8; o > 0; o >>= 1) m = fmaxf(m, __shfl_xor(m, o));
    float sum = 0.f;
#pragma unroll
    for (int f = 0; f < 6; ++f) { ev[f][r] = __expf(ev[f][r] - m); sum += ev[f][r]; }
#pragma unroll
    for (int o = 8; o > 0; o >>= 1) sum += __shfl_xor(sum, o);
    inv[r] = 1.0f / sum;
  }
#pragma unroll
  for (int f = 0; f < 6; ++f)
#pragma unroll
    for (int r = 0; r < 4; ++r)
      Ps[wave][g * 4 + r][fr + 16 * f] = (__bf16)ev[f][r];
  asm volatile("s_waitcnt lgkmcnt(0)" ::: "memory");
  f32x4 o0 = {0.f, 0.f, 0.f, 0.f}, o1 = {0.f, 0.f, 0.f, 0.f};
#pragma unroll
  for (int s = 0; s < 3; ++s) {
    const bf16x8 pa  = *(const bf16x8*)&Ps[wave][fr][s * 32 + g * 8];
    const bf16x8 vb0 = *(const bf16x8*)&Vt[fr][s * 32 + g * 8];
    const bf16x8 vb1 = *(const bf16x8*)&Vt[16 + fr][s * 32 + g * 8];
    o0 = __builtin_amdgcn_mfma_f32_16x16x32_bf16(pa, vb0, o0, 0, 0, 0);
    o1 = __builtin_amdgcn_mfma_f32_16x16x32_bf16(pa, vb1, o1, 0, 0, 0);
  }
  const size_t orow = (slab + q0 + g * 4) * 256 + h * 32;
#pragma unroll
  for (int r = 0; r < 4; ++r) {
    ctx[orow + (size_t)r * 256 + fr]      = __float2bfloat16(o0[r] * inv[r]);
    ctx[orow + (size_t)r * 256 + 16 + fr] = __float2bfloat16(o1[r] * inv[r]);
  }
}

extern "C" void kernel_launch(void* const* d_in, const int* in_sizes, int n_in,
                              void* d_out, int out_size, void* d_ws, size_t ws_size,
                              hipStream_t stream) {
  (void)in_sizes; (void)n_in; (void)out_size; (void)ws_size;
  const float* table = (const float*)d_in[0];
  const float* depm  = (const float*)d_in[1];
  const float* Wq = (const float*)d_in[2];   const float* bq = (const float*)d_in[3];
  const float* Wk = (const float*)d_in[4];   const float* bk = (const float*)d_in[5];
  const float* Wv = (const float*)d_in[6];   const float* bv = (const float*)d_in[7];
  const float* Wo = (const float*)d_in[8];   const float* bo = (const float*)d_in[9];
  const float* Wdep = (const float*)d_in[10]; const float* bdep = (const float*)d_in[11];
  const float* g1 = (const float*)d_in[12];  const float* be1 = (const float*)d_in[13];
  const float* W1 = (const float*)d_in[14];  const float* b1 = (const float*)d_in[15];
  const float* W2 = (const float*)d_in[16];  const float* b2 = (const float*)d_in[17];
  const float* g2 = (const float*)d_in[18];  const float* be2 = (const float*)d_in[19];

  char* ws = (char*)d_ws;
  size_t off = 0;
  __bf16* qkvb  = (__bf16*)(ws + off); off += (size_t)M_ROWS * 768 * 2;   // 56.6MB
  __bf16* ctxb  = (__bf16*)(ws + off); off += (size_t)M_ROWS * 256 * 2;   // 18.9MB
  __bf16* pre1b = (__bf16*)(ws + off); off += (size_t)M_ROWS * 256 * 2;   // 18.9MB
  __bf16* outbb = (__bf16*)(ws + off); off += (size_t)M_ROWS * 256 * 2;   // 18.9MB
  __bf16* hidb  = (__bf16*)(ws + off); off += (size_t)M_ROWS * 1024 * 2;  // 75.5MB
  __bf16* pre2b = (__bf16*)(ws + off); off += (size_t)M_ROWS * 256 * 2;   // 18.9MB
  __bf16* tabb  = (__bf16*)(ws + off); off += (size_t)M_ROWS * 256 * 2;   // 18.9MB
  __bf16* Wqkv_t = (__bf16*)(ws + off); off += 768 * 256 * 2;
  __bf16* Wo_t   = (__bf16*)(ws + off); off += 256 * 256 * 2;
  __bf16* W1_t   = (__bf16*)(ws + off); off += 1024 * 256 * 2;
  __bf16* W2_t   = (__bf16*)(ws + off); off += 256 * 1024 * 2;
  float*  bqkv   = (float*)(ws + off);

  cvt_bf16_kernel<<<4608, 256, 0, stream>>>(table, tabb, M_ROWS * 256 / 8);
  pack_w_kernel<<<3072, 256, 0, stream>>>(Wq, Wk, Wv, Wo, W1, W2, bq, bk, bv,
                                          Wqkv_t, Wo_t, W1_t, W2_t, bqkv);
  // qkv = table @ Wqkv + bqkv -> bf16 [M,768]
  gemm_k64_kernel<0><<<dim3(6, 576), 256, 0, stream>>>(
      tabb, Wqkv_t, bqkv, nullptr, (__hip_bfloat16*)qkvb, 768, 256);
  // attention -> ctx bf16 [M,256]
  attn_mfma_kernel<<<3072, 384, 0, stream>>>(qkvb, depm, Wdep, bdep, (__hip_bfloat16*)ctxb);
  // pre1 = ctx @ Wo + bo + table(bf16 resid)
  gemm_k64_kernel<2><<<dim3(2, 576), 256, 0, stream>>>(
      ctxb, Wo_t, bo, tabb, (__hip_bfloat16*)pre1b, 256, 256);
  // outbb = LN1(pre1) (bf16)
  ln_bf16_kernel<false><<<9216, 256, 0, stream>>>(pre1b, g1, be1, outbb);
  // hidden = relu(outbb @ W1 + b1) -> bf16 [M,1024]
  gemm_k64_kernel<1><<<dim3(8, 576), 256, 0, stream>>>(
      outbb, W1_t, b1, nullptr, (__hip_bfloat16*)hidb, 1024, 256);
  // pre2 = hidden @ W2 + b2 + outbb(resid)
  gemm_k64_kernel<2><<<dim3(2, 576), 256, 0, stream>>>(
      hidb, W2_t, b2, outbb, (__hip_bfloat16*)pre2b, 256, 1024);
  // d_out = LN2(pre2) fp32
  ln_bf16_kernel<true><<<9216, 256, 0, stream>>>(pre2b, g2, be2, (float*)d_out);
}

// Round 10
// 175.249 us; speedup vs baseline: 1.3799x; 1.0423x over previous
//
#include <hip/hip_runtime.h>
#include <hip/hip_bf16.h>
#include <math.h>

// Problem constants: B=4, L=96, D=256, H=8, hd=32, FF=1024. M = B*L*L = 36864.
#define M_ROWS 36864

typedef __bf16 bf16x8 __attribute__((ext_vector_type(8)));
typedef __bf16 bf16x4 __attribute__((ext_vector_type(4)));
typedef float f32x4 __attribute__((ext_vector_type(4)));

__device__ __forceinline__ void gload16(const void* g, void* l) {
  __builtin_amdgcn_global_load_lds((const __attribute__((address_space(1))) void*)g,
                                   (__attribute__((address_space(3))) void*)l, 16, 0, 0);
}

// ---------------- pack + transpose weights to bf16 B^T [N,K] ----------------
__global__ __launch_bounds__(256) void pack_w_kernel(
    const float* __restrict__ Wq, const float* __restrict__ Wk, const float* __restrict__ Wv,
    const float* __restrict__ Wo, const float* __restrict__ W1, const float* __restrict__ W2,
    const float* __restrict__ bq, const float* __restrict__ bk, const float* __restrict__ bv,
    __bf16* __restrict__ Wqkv_t, __bf16* __restrict__ Wo_t,
    __bf16* __restrict__ W1_t, __bf16* __restrict__ W2_t, float* __restrict__ bqkv) {
  int idx = blockIdx.x * 256 + threadIdx.x;
  const int S1 = 768 * 256, S2 = 256 * 256, S3 = 1024 * 256;
  if (idx < S1) {
    int n = idx / 256, k = idx % 256;
    int sel = n >> 8, nn = n & 255;
    const float* W = (sel == 0) ? Wq : (sel == 1) ? Wk : Wv;
    Wqkv_t[idx] = (__bf16)W[k * 256 + nn];
  } else if (idx < S1 + S2) {
    int j = idx - S1; int n = j / 256, k = j % 256;
    Wo_t[j] = (__bf16)Wo[k * 256 + n];
  } else if (idx < S1 + S2 + S3) {
    int j = idx - S1 - S2; int n = j / 256, k = j % 256;
    W1_t[j] = (__bf16)W1[k * 1024 + n];
  } else {
    int j = idx - S1 - S2 - S3; int n = j / 1024, k = j % 1024;
    W2_t[j] = (__bf16)W2[k * 256 + n];
  }
  if (idx < 768) {
    int sel = idx >> 8, jj = idx & 255;
    const float* bsrc = (sel == 0) ? bq : (sel == 1) ? bk : bv;
    bqkv[idx] = bsrc[jj];
  }
}

// -------- MFMA GEMM: BM=64 x BN=128, BK=64, 4 waves, 24KB LDS -----------------
// AF32: A is fp32, reg-staged with on-the-fly bf16 convert (kills cvt pass).
// EPI: 0 = bias -> bf16, 1 = bias+relu -> bf16.
template <int EPI, bool AF32>
__global__ __launch_bounds__(256, 4) void gemm_k64_kernel(
    const void* __restrict__ Av, const __bf16* __restrict__ Bt,
    const float* __restrict__ bias, __hip_bfloat16* __restrict__ Y, int N, int K) {
  __shared__ __bf16 As[64 * 64];    // 8KB
  __shared__ __bf16 Bs[128 * 64];   // 16KB
  const int tid = threadIdx.x;
  const int lane = tid & 63, wv = tid >> 6;
  const int wm = wv >> 1, wn = wv & 1;
  const int gx = gridDim.x;
  const int nwg = gx * gridDim.y;
  int lin = blockIdx.y * gx + blockIdx.x;
  lin = (lin & 7) * (nwg >> 3) + (lin >> 3);
  const int n0 = (lin % gx) * 128;
  const int m0 = (lin / gx) * 64;
  const int fr = lane & 15, g = lane >> 4;
  const int lrow8 = lane >> 3;                               // 0..7
  const int gs = (lane & 7) ^ lrow8;                         // swizzled granule idx
  const int gseg = gs * 8;

  f32x4 acc[2][4] = {};
  const int nph = K >> 6;

  for (int p = 0; p < nph; ++p) {
    const int kb = p * 64;
    __syncthreads();   // all waves done reading previous phase's LDS
    if (AF32) {
      const float* Af = (const float*)Av;
      // row0 = m0+wv*16+lrow8, row1 = row0+8; same granule (row&7 == lrow8)
      const float* s0 = &Af[(size_t)(m0 + wv * 16 + lrow8) * K + kb + gseg];
      const float* s1 = &Af[(size_t)(m0 + wv * 16 + 8 + lrow8) * K + kb + gseg];
      float4 a0 = *(const float4*)s0, a1 = *(const float4*)(s0 + 4);
      float4 b0 = *(const float4*)s1, b1 = *(const float4*)(s1 + 4);
      bf16x8 o0 = {(__bf16)a0.x, (__bf16)a0.y, (__bf16)a0.z, (__bf16)a0.w,
                   (__bf16)a1.x, (__bf16)a1.y, (__bf16)a1.z, (__bf16)a1.w};
      bf16x8 o1 = {(__bf16)b0.x, (__bf16)b0.y, (__bf16)b0.z, (__bf16)b0.w,
                   (__bf16)b1.x, (__bf16)b1.y, (__bf16)b1.z, (__bf16)b1.w};
      *(bf16x8*)&As[wv * 1024 + lane * 8] = o0;
      *(bf16x8*)&As[wv * 1024 + 512 + lane * 8] = o1;
    } else {
      const __bf16* Ab = (const __bf16*)Av;
      gload16(Ab + (size_t)(m0 + wv * 16 + lrow8) * K + kb + gseg,     &As[wv * 1024]);
      gload16(Ab + (size_t)(m0 + wv * 16 + 8 + lrow8) * K + kb + gseg, &As[wv * 1024 + 512]);
    }
#pragma unroll
    for (int j = 0; j < 4; ++j)
      gload16(Bt + (size_t)(n0 + wv * 32 + j * 8 + lrow8) * K + kb + gseg,
              &Bs[wv * 2048 + j * 512]);
    __syncthreads();   // drains vmcnt + lgkmcnt: staged data visible
#pragma unroll
    for (int s = 0; s < 2; ++s) {
      bf16x8 av[2], bv[4];
      const int cs = ((s * 4 + g) ^ (fr & 7)) * 8;
#pragma unroll
      for (int mi = 0; mi < 2; ++mi)
        av[mi] = *reinterpret_cast<const bf16x8*>(&As[(wm * 32 + mi * 16 + fr) * 64 + cs]);
#pragma unroll
      for (int ni = 0; ni < 4; ++ni)
        bv[ni] = *reinterpret_cast<const bf16x8*>(&Bs[(wn * 64 + ni * 16 + fr) * 64 + cs]);
#pragma unroll
      for (int mi = 0; mi < 2; ++mi)
#pragma unroll
        for (int ni = 0; ni < 4; ++ni)
          acc[mi][ni] = __builtin_amdgcn_mfma_f32_16x16x32_bf16(av[mi], bv[ni], acc[mi][ni], 0, 0, 0);
    }
  }

  const int crow = m0 + wm * 32 + g * 4;
  const int ccol = n0 + wn * 64 + fr;
#pragma unroll
  for (int mi = 0; mi < 2; ++mi) {
#pragma unroll
    for (int ni = 0; ni < 4; ++ni) {
      const int col = ccol + ni * 16;
      const float bb = bias[col];
#pragma unroll
      for (int r = 0; r < 4; ++r) {
        const int row = crow + mi * 16 + r;
        float v = acc[mi][ni][r] + bb;
        if (EPI == 1) v = fmaxf(v, 0.f);
        Y[(size_t)row * N + col] = __float2bfloat16(v);
      }
    }
  }
}

// ---- GEMM (N=256) + bias + resid + LayerNorm: BM=32 x BN=256, 4 waves --------
// 1152 blocks -> 4.5/CU (the proven TLP regime). Wave wv owns cols wv*64..+63.
// LN is block-local: 16-lane shfl partials + tiny LDS cross-wave reduce.
// RESID_F32: residual fp32 (table) vs bf16. OUT_F32: fp32 out (d_out) vs bf16.
template <bool RESID_F32, bool OUT_F32>
__global__ __launch_bounds__(256, 4) void gemm_ln32_kernel(
    const __bf16* __restrict__ A, const __bf16* __restrict__ Bt,
    const float* __restrict__ bias, const void* __restrict__ residv,
    const float* __restrict__ gamma, const float* __restrict__ beta,
    void* __restrict__ Y, int K) {
  __shared__ __bf16 As[32 * 64];    // 4KB
  __shared__ __bf16 Bs[256 * 64];   // 32KB
  __shared__ float red[2][4][32];   // {sum,sumsq}[wave][row]
  const int tid = threadIdx.x;
  const int lane = tid & 63, wv = tid >> 6;
  const int nwg = gridDim.x;
  int lin = blockIdx.x;
  lin = (lin & 7) * (nwg >> 3) + (lin >> 3);
  const int m0 = lin * 32;
  const int fr = lane & 15, g = lane >> 4;
  const int lrow8 = lane >> 3;
  const int gseg = ((lane & 7) ^ lrow8) * 8;

  f32x4 acc[2][4] = {};
  const int nph = K >> 6;

  for (int p = 0; p < nph; ++p) {
    const int kb = p * 64;
    __syncthreads();
    // A: 32 rows; wave wv stages rows wv*8..+7 (one gload16/thread)
    gload16(A + (size_t)(m0 + wv * 8 + lrow8) * K + kb + gseg, &As[wv * 512]);
    // B: 256 rows; wave wv stages rows wv*64..+63 (8 gload16/thread)
#pragma unroll
    for (int j = 0; j < 8; ++j)
      gload16(Bt + (size_t)(wv * 64 + j * 8 + lrow8) * K + kb + gseg,
              &Bs[wv * 4096 + j * 512]);
    __syncthreads();
#pragma unroll
    for (int s = 0; s < 2; ++s) {
      bf16x8 av[2], bv[4];
      const int cs = ((s * 4 + g) ^ (fr & 7)) * 8;
#pragma unroll
      for (int mi = 0; mi < 2; ++mi)
        av[mi] = *reinterpret_cast<const bf16x8*>(&As[(mi * 16 + fr) * 64 + cs]);
#pragma unroll
      for (int ni = 0; ni < 4; ++ni)
        bv[ni] = *reinterpret_cast<const bf16x8*>(&Bs[(wv * 64 + ni * 16 + fr) * 64 + cs]);
#pragma unroll
      for (int mi = 0; mi < 2; ++mi)
#pragma unroll
        for (int ni = 0; ni < 4; ++ni)
          acc[mi][ni] = __builtin_amdgcn_mfma_f32_16x16x32_bf16(av[mi], bv[ni], acc[mi][ni], 0, 0, 0);
    }
  }

  // ---- epilogue: v = acc + bias + resid; LN over 256 cols per row ----
  const int colb = wv * 64 + fr;  // + ni*16
  float bb[4], gg[4], be[4];
#pragma unroll
  for (int ni = 0; ni < 4; ++ni) {
    bb[ni] = bias[colb + ni * 16];
    gg[ni] = gamma[colb + ni * 16];
    be[ni] = beta[colb + ni * 16];
  }
#pragma unroll
  for (int mi = 0; mi < 2; ++mi) {
#pragma unroll
    for (int r = 0; r < 4; ++r) {
      const int lr = mi * 16 + g * 4 + r;          // 0..31
      const size_t grow = (size_t)(m0 + lr) * 256;
      float s = 0.f, q = 0.f;
#pragma unroll
      for (int ni = 0; ni < 4; ++ni) {
        const int col = colb + ni * 16;
        const float rr = RESID_F32 ? ((const float*)residv)[grow + col]
                                   : (float)((const __bf16*)residv)[grow + col];
        float v = acc[mi][ni][r] + bb[ni] + rr;
        acc[mi][ni][r] = v;
        s += v; q += v * v;
      }
#pragma unroll
      for (int o = 8; o > 0; o >>= 1) { s += __shfl_xor(s, o); q += __shfl_xor(q, o); }
      if (fr == 0) { red[0][wv][lr] = s; red[1][wv][lr] = q; }
    }
  }
  __syncthreads();
#pragma unroll
  for (int mi = 0; mi < 2; ++mi) {
#pragma unroll
    for (int r = 0; r < 4; ++r) {
      const int lr = mi * 16 + g * 4 + r;
      const size_t grow = (size_t)(m0 + lr) * 256;
      const float s = red[0][0][lr] + red[0][1][lr] + red[0][2][lr] + red[0][3][lr];
      const float q = red[1][0][lr] + red[1][1][lr] + red[1][2][lr] + red[1][3][lr];
      const float mean = s * (1.0f / 256.0f);
      const float var = q * (1.0f / 256.0f) - mean * mean;
      const float inv = rsqrtf(var + 1e-5f);
#pragma unroll
      for (int ni = 0; ni < 4; ++ni) {
        const float y = (acc[mi][ni][r] - mean) * inv * gg[ni] + be[ni];
        if (OUT_F32) ((float*)Y)[grow + colb + ni * 16] = y;
        else ((__hip_bfloat16*)Y)[grow + colb + ni * 16] = __float2bfloat16(y);
      }
    }
  }
}

// ---------------- MFMA attention: one block per (b,h,x), 6 waves ----------------
__global__ __launch_bounds__(384) void attn_mfma_kernel(
    const __bf16* __restrict__ qkv, const float* __restrict__ depm,
    const float* __restrict__ Wdep, const float* __restrict__ bdep,
    __hip_bfloat16* __restrict__ ctx) {
  __shared__ __bf16 Qs[96][40];
  __shared__ __bf16 Ks[96][40];
  __shared__ __bf16 Vt[32][104];
  __shared__ __bf16 Ps[6][16][104];
  int lin = blockIdx.x;
  lin = (lin & 7) * 384 + (lin >> 3);
  const int h = lin & 7;
  const int sx = lin >> 3;
  const int x = sx % 96;
  const int b = sx / 96;
  const int tid = threadIdx.x;
  const size_t slab = (size_t)(b * 96 + x) * 96;
  const size_t base = slab * 768 + h * 32;
#pragma unroll
  for (int t = 0; t < 3; ++t) {
    const int idx = tid + t * 384;
    const int r = idx / 12, rem = idx % 12, mat = rem >> 2, seg = rem & 3;
    const int d0 = seg * 8;
    bf16x8 v8 = *(const bf16x8*)&qkv[base + (size_t)r * 768 + mat * 256 + d0];
    if (mat == 0)      *(bf16x8*)&Qs[r][d0] = v8;
    else if (mat == 1) *(bf16x8*)&Ks[r][d0] = v8;
    else {
#pragma unroll
      for (int e = 0; e < 8; ++e) Vt[d0 + e][r] = v8[e];
    }
  }
  __syncthreads();
  const int wave = tid >> 6, lane = tid & 63;
  const int fr = lane & 15, g = lane >> 4;
  const int q0 = wave * 16;
  const float wd = Wdep[h], bd = bdep[h];
  float depb[6];
#pragma unroll
  for (int f = 0; f < 6; ++f) depb[f] = depm[slab + fr + 16 * f] * wd + bd;
  const bf16x8 av = *(const bf16x8*)&Qs[q0 + fr][g * 8];
  f32x4 sacc[6];
#pragma unroll
  for (int f = 0; f < 6; ++f) {
    const bf16x8 bv = *(const bf16x8*)&Ks[f * 16 + fr][g * 8];
    sacc[f] = __builtin_amdgcn_mfma_f32_16x16x32_bf16(av, bv, (f32x4){0.f, 0.f, 0.f, 0.f}, 0, 0, 0);
  }
  const float scale = 0.17677669529663687f;
  float ev[6][4];
  float inv[4];
#pragma unroll
  for (int r = 0; r < 4; ++r) {
    float m = -1e30f;
#pragma unroll
    for (int f = 0; f < 6; ++f) {
      ev[f][r] = sacc[f][r] * scale + depb[f];
      m = fmaxf(m, ev[f][r]);
    }
#pragma unroll
    for (int o = 8; o > 0; o >>= 1) m = fmaxf(m, __shfl_xor(m, o));
    float sum = 0.f;
#pragma unroll
    for (int f = 0; f < 6; ++f) { ev[f][r] = __expf(ev[f][r] - m); sum += ev[f][r]; }
#pragma unroll
    for (int o = 8; o > 0; o >>= 1) sum += __shfl_xor(sum, o);
    inv[r] = 1.0f / sum;
  }
#pragma unroll
  for (int f = 0; f < 6; ++f)
#pragma unroll
    for (int r = 0; r < 4; ++r)
      Ps[wave][g * 4 + r][fr + 16 * f] = (__bf16)ev[f][r];
  asm volatile("s_waitcnt lgkmcnt(0)" ::: "memory");
  f32x4 o0 = {0.f, 0.f, 0.f, 0.f}, o1 = {0.f, 0.f, 0.f, 0.f};
#pragma unroll
  for (int s = 0; s < 3; ++s) {
    const bf16x8 pa  = *(const bf16x8*)&Ps[wave][fr][s * 32 + g * 8];
    const bf16x8 vb0 = *(const bf16x8*)&Vt[fr][s * 32 + g * 8];
    const bf16x8 vb1 = *(const bf16x8*)&Vt[16 + fr][s * 32 + g * 8];
    o0 = __builtin_amdgcn_mfma_f32_16x16x32_bf16(pa, vb0, o0, 0, 0, 0);
    o1 = __builtin_amdgcn_mfma_f32_16x16x32_bf16(pa, vb1, o1, 0, 0, 0);
  }
  const size_t orow = (slab + q0 + g * 4) * 256 + h * 32;
#pragma unroll
  for (int r = 0; r < 4; ++r) {
    ctx[orow + (size_t)r * 256 + fr]      = __float2bfloat16(o0[r] * inv[r]);
    ctx[orow + (size_t)r * 256 + 16 + fr] = __float2bfloat16(o1[r] * inv[r]);
  }
}

extern "C" void kernel_launch(void* const* d_in, const int* in_sizes, int n_in,
                              void* d_out, int out_size, void* d_ws, size_t ws_size,
                              hipStream_t stream) {
  (void)in_sizes; (void)n_in; (void)out_size; (void)ws_size;
  const float* table = (const float*)d_in[0];
  const float* depm  = (const float*)d_in[1];
  const float* Wq = (const float*)d_in[2];   const float* bq = (const float*)d_in[3];
  const float* Wk = (const float*)d_in[4];   const float* bk = (const float*)d_in[5];
  const float* Wv = (const float*)d_in[6];   const float* bv = (const float*)d_in[7];
  const float* Wo = (const float*)d_in[8];   const float* bo = (const float*)d_in[9];
  const float* Wdep = (const float*)d_in[10]; const float* bdep = (const float*)d_in[11];
  const float* g1 = (const float*)d_in[12];  const float* be1 = (const float*)d_in[13];
  const float* W1 = (const float*)d_in[14];  const float* b1 = (const float*)d_in[15];
  const float* W2 = (const float*)d_in[16];  const float* b2 = (const float*)d_in[17];
  const float* g2 = (const float*)d_in[18];  const float* be2 = (const float*)d_in[19];

  char* ws = (char*)d_ws;
  size_t off = 0;
  __bf16* qkvb  = (__bf16*)(ws + off); off += (size_t)M_ROWS * 768 * 2;   // 56.6MB
  __bf16* ctxb  = (__bf16*)(ws + off); off += (size_t)M_ROWS * 256 * 2;   // 18.9MB
  __bf16* outbb = (__bf16*)(ws + off); off += (size_t)M_ROWS * 256 * 2;   // 18.9MB
  __bf16* hidb  = (__bf16*)(ws + off); off += (size_t)M_ROWS * 1024 * 2;  // 75.5MB
  __bf16* Wqkv_t = (__bf16*)(ws + off); off += 768 * 256 * 2;
  __bf16* Wo_t   = (__bf16*)(ws + off); off += 256 * 256 * 2;
  __bf16* W1_t   = (__bf16*)(ws + off); off += 1024 * 256 * 2;
  __bf16* W2_t   = (__bf16*)(ws + off); off += 256 * 1024 * 2;
  float*  bqkv   = (float*)(ws + off);

  pack_w_kernel<<<3072, 256, 0, stream>>>(Wq, Wk, Wv, Wo, W1, W2, bq, bk, bv,
                                          Wqkv_t, Wo_t, W1_t, W2_t, bqkv);
  // qkv = table(fp32, reg-staged cvt) @ Wqkv + bqkv -> bf16 [M,768]
  gemm_k64_kernel<0, true><<<dim3(6, 576), 256, 0, stream>>>(
      table, Wqkv_t, bqkv, (__hip_bfloat16*)qkvb, 768, 256);
  // attention -> ctx bf16 [M,256]
  attn_mfma_kernel<<<3072, 384, 0, stream>>>(qkvb, depm, Wdep, bdep, (__hip_bfloat16*)ctxb);
  // outbb = LN1(ctx @ Wo + bo + table[fp32 resid])  [fused, bf16 out]
  gemm_ln32_kernel<true, false><<<1152, 256, 0, stream>>>(
      ctxb, Wo_t, bo, table, g1, be1, outbb, 256);
  // hidden = relu(outbb @ W1 + b1) -> bf16 [M,1024]
  gemm_k64_kernel<1, false><<<dim3(8, 576), 256, 0, stream>>>(
      outbb, W1_t, b1, (__hip_bfloat16*)hidb, 1024, 256);
  // d_out = LN2(hidden @ W2 + b2 + outbb[bf16 resid])  [fused, fp32 out]
  gemm_ln32_kernel<false, true><<<1152, 256, 0, stream>>>(
      hidb, W2_t, b2, outbb, g2, be2, (float*)d_out, 1024);
}

// Round 11
// 168.394 us; speedup vs baseline: 1.4361x; 1.0407x over previous
//
#include <hip/hip_runtime.h>
#include <hip/hip_bf16.h>
#include <math.h>

// Problem constants: B=4, L=96, D=256, H=8, hd=32, FF=1024. M = B*L*L = 36864.
#define M_ROWS 36864

typedef __bf16 bf16x8 __attribute__((ext_vector_type(8)));
typedef __bf16 bf16x4 __attribute__((ext_vector_type(4)));
typedef float f32x4 __attribute__((ext_vector_type(4)));

__device__ __forceinline__ void gload16(const void* g, void* l) {
  __builtin_amdgcn_global_load_lds((const __attribute__((address_space(1))) void*)g,
                                   (__attribute__((address_space(3))) void*)l, 16, 0, 0);
}

// ---------------- pack + transpose weights to bf16 B^T [N,K] ----------------
__global__ __launch_bounds__(256) void pack_w_kernel(
    const float* __restrict__ Wq, const float* __restrict__ Wk, const float* __restrict__ Wv,
    const float* __restrict__ Wo, const float* __restrict__ W1, const float* __restrict__ W2,
    const float* __restrict__ bq, const float* __restrict__ bk, const float* __restrict__ bv,
    __bf16* __restrict__ Wqkv_t, __bf16* __restrict__ Wo_t,
    __bf16* __restrict__ W1_t, __bf16* __restrict__ W2_t, float* __restrict__ bqkv) {
  int idx = blockIdx.x * 256 + threadIdx.x;
  const int S1 = 768 * 256, S2 = 256 * 256, S3 = 1024 * 256;
  if (idx < S1) {
    int n = idx / 256, k = idx % 256;
    int sel = n >> 8, nn = n & 255;
    const float* W = (sel == 0) ? Wq : (sel == 1) ? Wk : Wv;
    Wqkv_t[idx] = (__bf16)W[k * 256 + nn];
  } else if (idx < S1 + S2) {
    int j = idx - S1; int n = j / 256, k = j % 256;
    Wo_t[j] = (__bf16)Wo[k * 256 + n];
  } else if (idx < S1 + S2 + S3) {
    int j = idx - S1 - S2; int n = j / 256, k = j % 256;
    W1_t[j] = (__bf16)W1[k * 1024 + n];
  } else {
    int j = idx - S1 - S2 - S3; int n = j / 1024, k = j % 1024;
    W2_t[j] = (__bf16)W2[k * 256 + n];
  }
  if (idx < 768) {
    int sel = idx >> 8, jj = idx & 255;
    const float* bsrc = (sel == 0) ? bq : (sel == 1) ? bk : bv;
    bqkv[idx] = bsrc[jj];
  }
}

// -------- MFMA GEMM: BM=64 x BN=128, BK=64, 4 waves, 24KB LDS -----------------
// AF32: A is fp32, reg-staged with on-the-fly bf16 convert (kills cvt pass).
// EPI: 0 = bias -> bf16, 1 = bias+relu -> bf16.
template <int EPI, bool AF32>
__global__ __launch_bounds__(256, 4) void gemm_k64_kernel(
    const void* __restrict__ Av, const __bf16* __restrict__ Bt,
    const float* __restrict__ bias, __hip_bfloat16* __restrict__ Y, int N, int K) {
  __shared__ __bf16 As[64 * 64];    // 8KB
  __shared__ __bf16 Bs[128 * 64];   // 16KB
  const int tid = threadIdx.x;
  const int lane = tid & 63, wv = tid >> 6;
  const int wm = wv >> 1, wn = wv & 1;
  const int gx = gridDim.x;
  const int nwg = gx * gridDim.y;
  int lin = blockIdx.y * gx + blockIdx.x;
  lin = (lin & 7) * (nwg >> 3) + (lin >> 3);
  const int n0 = (lin % gx) * 128;
  const int m0 = (lin / gx) * 64;
  const int fr = lane & 15, g = lane >> 4;
  const int lrow8 = lane >> 3;                               // 0..7
  const int gseg = ((lane & 7) ^ lrow8) * 8;                 // pre-swizzled src col

  f32x4 acc[2][4] = {};
  const int nph = K >> 6;

  for (int p = 0; p < nph; ++p) {
    const int kb = p * 64;
    __syncthreads();   // all waves done reading previous phase's LDS
    if (AF32) {
      const float* Af = (const float*)Av;
      const float* s0 = &Af[(size_t)(m0 + wv * 16 + lrow8) * K + kb + gseg];
      const float* s1 = &Af[(size_t)(m0 + wv * 16 + 8 + lrow8) * K + kb + gseg];
      float4 a0 = *(const float4*)s0, a1 = *(const float4*)(s0 + 4);
      float4 b0 = *(const float4*)s1, b1 = *(const float4*)(s1 + 4);
      bf16x8 o0 = {(__bf16)a0.x, (__bf16)a0.y, (__bf16)a0.z, (__bf16)a0.w,
                   (__bf16)a1.x, (__bf16)a1.y, (__bf16)a1.z, (__bf16)a1.w};
      bf16x8 o1 = {(__bf16)b0.x, (__bf16)b0.y, (__bf16)b0.z, (__bf16)b0.w,
                   (__bf16)b1.x, (__bf16)b1.y, (__bf16)b1.z, (__bf16)b1.w};
      *(bf16x8*)&As[wv * 1024 + lane * 8] = o0;
      *(bf16x8*)&As[wv * 1024 + 512 + lane * 8] = o1;
    } else {
      const __bf16* Ab = (const __bf16*)Av;
      gload16(Ab + (size_t)(m0 + wv * 16 + lrow8) * K + kb + gseg,     &As[wv * 1024]);
      gload16(Ab + (size_t)(m0 + wv * 16 + 8 + lrow8) * K + kb + gseg, &As[wv * 1024 + 512]);
    }
#pragma unroll
    for (int j = 0; j < 4; ++j)
      gload16(Bt + (size_t)(n0 + wv * 32 + j * 8 + lrow8) * K + kb + gseg,
              &Bs[wv * 2048 + j * 512]);
    __syncthreads();   // drains vmcnt + lgkmcnt: staged data visible
#pragma unroll
    for (int s = 0; s < 2; ++s) {
      bf16x8 av[2], bv[4];
      const int cs = ((s * 4 + g) ^ (fr & 7)) * 8;
#pragma unroll
      for (int mi = 0; mi < 2; ++mi)
        av[mi] = *reinterpret_cast<const bf16x8*>(&As[(wm * 32 + mi * 16 + fr) * 64 + cs]);
#pragma unroll
      for (int ni = 0; ni < 4; ++ni)
        bv[ni] = *reinterpret_cast<const bf16x8*>(&Bs[(wn * 64 + ni * 16 + fr) * 64 + cs]);
#pragma unroll
      for (int mi = 0; mi < 2; ++mi)
#pragma unroll
        for (int ni = 0; ni < 4; ++ni)
          acc[mi][ni] = __builtin_amdgcn_mfma_f32_16x16x32_bf16(av[mi], bv[ni], acc[mi][ni], 0, 0, 0);
    }
  }

  const int crow = m0 + wm * 32 + g * 4;
  const int ccol = n0 + wn * 64 + fr;
#pragma unroll
  for (int mi = 0; mi < 2; ++mi) {
#pragma unroll
    for (int ni = 0; ni < 4; ++ni) {
      const int col = ccol + ni * 16;
      const float bb = bias[col];
#pragma unroll
      for (int r = 0; r < 4; ++r) {
        const int row = crow + mi * 16 + r;
        float v = acc[mi][ni][r] + bb;
        if (EPI == 1) v = fmaxf(v, 0.f);
        Y[(size_t)row * N + col] = __float2bfloat16(v);
      }
    }
  }
}

// ---- GEMM (N=256) + bias + resid + LayerNorm: BM=64 x BN=256, 8 waves --------
// 576 blocks, 512 threads; LDS 42KB -> 3 blocks/CU (~24 waves/CU).
// Key arithmetic: total B-staging = (M/BM)*N*K*2 -- BM=64 halves it vs BM=32.
// Wave grid 2M x 4N; per-wave 32x64 (2x4 frags). LN block-local as before.
// RESID_F32: residual fp32 (table) vs bf16. OUT_F32: fp32 out (d_out) vs bf16.
template <bool RESID_F32, bool OUT_F32>
__global__ __launch_bounds__(512, 6) void gemm_ln64_kernel(
    const __bf16* __restrict__ A, const __bf16* __restrict__ Bt,
    const float* __restrict__ bias, const void* __restrict__ residv,
    const float* __restrict__ gamma, const float* __restrict__ beta,
    void* __restrict__ Y, int K) {
  __shared__ __bf16 As[64 * 64];    // 8KB
  __shared__ __bf16 Bs[256 * 64];   // 32KB
  __shared__ float red[2][4][64];   // {sum,sumsq}[wn][row]  (2KB)
  const int tid = threadIdx.x;
  const int lane = tid & 63, wv = tid >> 6;       // wv 0..7
  const int wm = wv >> 2, wn = wv & 3;
  const int nwg = gridDim.x;
  int lin = blockIdx.x;
  lin = (lin & 7) * (nwg >> 3) + (lin >> 3);
  const int m0 = lin * 64;
  const int fr = lane & 15, g = lane >> 4;
  const int lrow8 = lane >> 3;                    // 0..7
  const int gseg = ((lane & 7) ^ lrow8) * 8;      // pre-swizzled src col

  f32x4 acc[2][4] = {};
  const int nph = K >> 6;

  for (int p = 0; p < nph; ++p) {
    const int kb = p * 64;
    __syncthreads();
    // A: 64 rows; wave wv stages rows wv*8..+7 (1 gload16/thread)
    gload16(A + (size_t)(m0 + wv * 8 + lrow8) * K + kb + gseg, &As[wv * 512]);
    // B: 256 rows; wave wv stages rows wv*32..+31 (4 gload16/thread)
#pragma unroll
    for (int j = 0; j < 4; ++j)
      gload16(Bt + (size_t)(wv * 32 + j * 8 + lrow8) * K + kb + gseg,
              &Bs[wv * 2048 + j * 512]);
    __syncthreads();
#pragma unroll
    for (int s = 0; s < 2; ++s) {
      bf16x8 av[2], bv[4];
      const int cs = ((s * 4 + g) ^ (fr & 7)) * 8;
#pragma unroll
      for (int mi = 0; mi < 2; ++mi)
        av[mi] = *reinterpret_cast<const bf16x8*>(&As[(wm * 32 + mi * 16 + fr) * 64 + cs]);
#pragma unroll
      for (int ni = 0; ni < 4; ++ni)
        bv[ni] = *reinterpret_cast<const bf16x8*>(&Bs[(wn * 64 + ni * 16 + fr) * 64 + cs]);
#pragma unroll
      for (int mi = 0; mi < 2; ++mi)
#pragma unroll
        for (int ni = 0; ni < 4; ++ni)
          acc[mi][ni] = __builtin_amdgcn_mfma_f32_16x16x32_bf16(av[mi], bv[ni], acc[mi][ni], 0, 0, 0);
    }
  }

  // ---- epilogue: v = acc + bias + resid; LN over 256 cols per row ----
  const int colb = wn * 64 + fr;  // + ni*16
  float bb[4], gg[4], be[4];
#pragma unroll
  for (int ni = 0; ni < 4; ++ni) {
    bb[ni] = bias[colb + ni * 16];
    gg[ni] = gamma[colb + ni * 16];
    be[ni] = beta[colb + ni * 16];
  }
#pragma unroll
  for (int mi = 0; mi < 2; ++mi) {
#pragma unroll
    for (int r = 0; r < 4; ++r) {
      const int lr = wm * 32 + mi * 16 + g * 4 + r;   // 0..63
      const size_t grow = (size_t)(m0 + lr) * 256;
      float s = 0.f, q = 0.f;
#pragma unroll
      for (int ni = 0; ni < 4; ++ni) {
        const int col = colb + ni * 16;
        const float rr = RESID_F32 ? ((const float*)residv)[grow + col]
                                   : (float)((const __bf16*)residv)[grow + col];
        float v = acc[mi][ni][r] + bb[ni] + rr;
        acc[mi][ni][r] = v;
        s += v; q += v * v;
      }
#pragma unroll
      for (int o = 8; o > 0; o >>= 1) { s += __shfl_xor(s, o); q += __shfl_xor(q, o); }
      if (fr == 0) { red[0][wn][lr] = s; red[1][wn][lr] = q; }
    }
  }
  __syncthreads();
#pragma unroll
  for (int mi = 0; mi < 2; ++mi) {
#pragma unroll
    for (int r = 0; r < 4; ++r) {
      const int lr = wm * 32 + mi * 16 + g * 4 + r;
      const size_t grow = (size_t)(m0 + lr) * 256;
      const float s = red[0][0][lr] + red[0][1][lr] + red[0][2][lr] + red[0][3][lr];
      const float q = red[1][0][lr] + red[1][1][lr] + red[1][2][lr] + red[1][3][lr];
      const float mean = s * (1.0f / 256.0f);
      const float var = q * (1.0f / 256.0f) - mean * mean;
      const float inv = rsqrtf(var + 1e-5f);
#pragma unroll
      for (int ni = 0; ni < 4; ++ni) {
        const float y = (acc[mi][ni][r] - mean) * inv * gg[ni] + be[ni];
        if (OUT_F32) ((float*)Y)[grow + colb + ni * 16] = y;
        else ((__hip_bfloat16*)Y)[grow + colb + ni * 16] = __float2bfloat16(y);
      }
    }
  }
}

// ---------------- MFMA attention: one block per (b,h,x), 6 waves ----------------
__global__ __launch_bounds__(384) void attn_mfma_kernel(
    const __bf16* __restrict__ qkv, const float* __restrict__ depm,
    const float* __restrict__ Wdep, const float* __restrict__ bdep,
    __hip_bfloat16* __restrict__ ctx) {
  __shared__ __bf16 Qs[96][40];
  __shared__ __bf16 Ks[96][40];
  __shared__ __bf16 Vt[32][104];
  __shared__ __bf16 Ps[6][16][104];
  int lin = blockIdx.x;
  lin = (lin & 7) * 384 + (lin >> 3);
  const int h = lin & 7;
  const int sx = lin >> 3;
  const int x = sx % 96;
  const int b = sx / 96;
  const int tid = threadIdx.x;
  const size_t slab = (size_t)(b * 96 + x) * 96;
  const size_t base = slab * 768 + h * 32;
#pragma unroll
  for (int t = 0; t < 3; ++t) {
    const int idx = tid + t * 384;
    const int r = idx / 12, rem = idx % 12, mat = rem >> 2, seg = rem & 3;
    const int d0 = seg * 8;
    bf16x8 v8 = *(const bf16x8*)&qkv[base + (size_t)r * 768 + mat * 256 + d0];
    if (mat == 0)      *(bf16x8*)&Qs[r][d0] = v8;
    else if (mat == 1) *(bf16x8*)&Ks[r][d0] = v8;
    else {
#pragma unroll
      for (int e = 0; e < 8; ++e) Vt[d0 + e][r] = v8[e];
    }
  }
  __syncthreads();
  const int wave = tid >> 6, lane = tid & 63;
  const int fr = lane & 15, g = lane >> 4;
  const int q0 = wave * 16;
  const float wd = Wdep[h], bd = bdep[h];
  float depb[6];
#pragma unroll
  for (int f = 0; f < 6; ++f) depb[f] = depm[slab + fr + 16 * f] * wd + bd;
  const bf16x8 av = *(const bf16x8*)&Qs[q0 + fr][g * 8];
  f32x4 sacc[6];
#pragma unroll
  for (int f = 0; f < 6; ++f) {
    const bf16x8 bv = *(const bf16x8*)&Ks[f * 16 + fr][g * 8];
    sacc[f] = __builtin_amdgcn_mfma_f32_16x16x32_bf16(av, bv, (f32x4){0.f, 0.f, 0.f, 0.f}, 0, 0, 0);
  }
  const float scale = 0.17677669529663687f;
  float ev[6][4];
  float inv[4];
#pragma unroll
  for (int r = 0; r < 4; ++r) {
    float m = -1e30f;
#pragma unroll
    for (int f = 0; f < 6; ++f) {
      ev[f][r] = sacc[f][r] * scale + depb[f];
      m = fmaxf(m, ev[f][r]);
    }
#pragma unroll
    for (int o = 8; o > 0; o >>= 1) m = fmaxf(m, __shfl_xor(m, o));
    float sum = 0.f;
#pragma unroll
    for (int f = 0; f < 6; ++f) { ev[f][r] = __expf(ev[f][r] - m); sum += ev[f][r]; }
#pragma unroll
    for (int o = 8; o > 0; o >>= 1) sum += __shfl_xor(sum, o);
    inv[r] = 1.0f / sum;
  }
#pragma unroll
  for (int f = 0; f < 6; ++f)
#pragma unroll
    for (int r = 0; r < 4; ++r)
      Ps[wave][g * 4 + r][fr + 16 * f] = (__bf16)ev[f][r];
  asm volatile("s_waitcnt lgkmcnt(0)" ::: "memory");
  f32x4 o0 = {0.f, 0.f, 0.f, 0.f}, o1 = {0.f, 0.f, 0.f, 0.f};
#pragma unroll
  for (int s = 0; s < 3; ++s) {
    const bf16x8 pa  = *(const bf16x8*)&Ps[wave][fr][s * 32 + g * 8];
    const bf16x8 vb0 = *(const bf16x8*)&Vt[fr][s * 32 + g * 8];
    const bf16x8 vb1 = *(const bf16x8*)&Vt[16 + fr][s * 32 + g * 8];
    o0 = __builtin_amdgcn_mfma_f32_16x16x32_bf16(pa, vb0, o0, 0, 0, 0);
    o1 = __builtin_amdgcn_mfma_f32_16x16x32_bf16(pa, vb1, o1, 0, 0, 0);
  }
  const size_t orow = (slab + q0 + g * 4) * 256 + h * 32;
#pragma unroll
  for (int r = 0; r < 4; ++r) {
    ctx[orow + (size_t)r * 256 + fr]      = __float2bfloat16(o0[r] * inv[r]);
    ctx[orow + (size_t)r * 256 + 16 + fr] = __float2bfloat16(o1[r] * inv[r]);
  }
}

extern "C" void kernel_launch(void* const* d_in, const int* in_sizes, int n_in,
                              void* d_out, int out_size, void* d_ws, size_t ws_size,
                              hipStream_t stream) {
  (void)in_sizes; (void)n_in; (void)out_size; (void)ws_size;
  const float* table = (const float*)d_in[0];
  const float* depm  = (const float*)d_in[1];
  const float* Wq = (const float*)d_in[2];   const float* bq = (const float*)d_in[3];
  const float* Wk = (const float*)d_in[4];   const float* bk = (const float*)d_in[5];
  const float* Wv = (const float*)d_in[6];   const float* bv = (const float*)d_in[7];
  const float* Wo = (const float*)d_in[8];   const float* bo = (const float*)d_in[9];
  const float* Wdep = (const float*)d_in[10]; const float* bdep = (const float*)d_in[11];
  const float* g1 = (const float*)d_in[12];  const float* be1 = (const float*)d_in[13];
  const float* W1 = (const float*)d_in[14];  const float* b1 = (const float*)d_in[15];
  const float* W2 = (const float*)d_in[16];  const float* b2 = (const float*)d_in[17];
  const float* g2 = (const float*)d_in[18];  const float* be2 = (const float*)d_in[19];

  char* ws = (char*)d_ws;
  size_t off = 0;
  __bf16* qkvb  = (__bf16*)(ws + off); off += (size_t)M_ROWS * 768 * 2;   // 56.6MB
  __bf16* ctxb  = (__bf16*)(ws + off); off += (size_t)M_ROWS * 256 * 2;   // 18.9MB
  __bf16* outbb = (__bf16*)(ws + off); off += (size_t)M_ROWS * 256 * 2;   // 18.9MB
  __bf16* hidb  = (__bf16*)(ws + off); off += (size_t)M_ROWS * 1024 * 2;  // 75.5MB
  __bf16* Wqkv_t = (__bf16*)(ws + off); off += 768 * 256 * 2;
  __bf16* Wo_t   = (__bf16*)(ws + off); off += 256 * 256 * 2;
  __bf16* W1_t   = (__bf16*)(ws + off); off += 1024 * 256 * 2;
  __bf16* W2_t   = (__bf16*)(ws + off); off += 256 * 1024 * 2;
  float*  bqkv   = (float*)(ws + off);

  pack_w_kernel<<<3072, 256, 0, stream>>>(Wq, Wk, Wv, Wo, W1, W2, bq, bk, bv,
                                          Wqkv_t, Wo_t, W1_t, W2_t, bqkv);
  // qkv = table(fp32, reg-staged cvt) @ Wqkv + bqkv -> bf16 [M,768]
  gemm_k64_kernel<0, true><<<dim3(6, 576), 256, 0, stream>>>(
      table, Wqkv_t, bqkv, (__hip_bfloat16*)qkvb, 768, 256);
  // attention -> ctx bf16 [M,256]
  attn_mfma_kernel<<<3072, 384, 0, stream>>>(qkvb, depm, Wdep, bdep, (__hip_bfloat16*)ctxb);
  // outbb = LN1(ctx @ Wo + bo + table[fp32 resid])  [fused, bf16 out]
  gemm_ln64_kernel<true, false><<<576, 512, 0, stream>>>(
      ctxb, Wo_t, bo, table, g1, be1, outbb, 256);
  // hidden = relu(outbb @ W1 + b1) -> bf16 [M,1024]
  gemm_k64_kernel<1, false><<<dim3(8, 576), 256, 0, stream>>>(
      outbb, W1_t, b1, (__hip_bfloat16*)hidb, 1024, 256);
  // d_out = LN2(hidden @ W2 + b2 + outbb[bf16 resid])  [fused, fp32 out]
  gemm_ln64_kernel<false, true><<<576, 512, 0, stream>>>(
      hidb, W2_t, b2, outbb, g2, be2, (float*)d_out, 1024);
}

// Round 12
// 167.632 us; speedup vs baseline: 1.4426x; 1.0045x over previous
//
#include <hip/hip_runtime.h>
#include <hip/hip_bf16.h>
#include <math.h>

// Problem constants: B=4, L=96, D=256, H=8, hd=32, FF=1024. M = B*L*L = 36864.
#define M_ROWS 36864

typedef __bf16 bf16x8 __attribute__((ext_vector_type(8)));
typedef __bf16 bf16x4 __attribute__((ext_vector_type(4)));
typedef float f32x4 __attribute__((ext_vector_type(4)));

__device__ __forceinline__ void gload16(const void* g, void* l) {
  __builtin_amdgcn_global_load_lds((const __attribute__((address_space(1))) void*)g,
                                   (__attribute__((address_space(3))) void*)l, 16, 0, 0);
}

// ---------------- pack + transpose weights to bf16 B^T [N,K] ----------------
__global__ __launch_bounds__(256) void pack_w_kernel(
    const float* __restrict__ Wq, const float* __restrict__ Wk, const float* __restrict__ Wv,
    const float* __restrict__ Wo, const float* __restrict__ W1, const float* __restrict__ W2,
    const float* __restrict__ bq, const float* __restrict__ bk, const float* __restrict__ bv,
    __bf16* __restrict__ Wqkv_t, __bf16* __restrict__ Wo_t,
    __bf16* __restrict__ W1_t, __bf16* __restrict__ W2_t, float* __restrict__ bqkv) {
  int idx = blockIdx.x * 256 + threadIdx.x;
  const int S1 = 768 * 256, S2 = 256 * 256, S3 = 1024 * 256;
  if (idx < S1) {
    int n = idx / 256, k = idx % 256;
    int sel = n >> 8, nn = n & 255;
    const float* W = (sel == 0) ? Wq : (sel == 1) ? Wk : Wv;
    Wqkv_t[idx] = (__bf16)W[k * 256 + nn];
  } else if (idx < S1 + S2) {
    int j = idx - S1; int n = j / 256, k = j % 256;
    Wo_t[j] = (__bf16)Wo[k * 256 + n];
  } else if (idx < S1 + S2 + S3) {
    int j = idx - S1 - S2; int n = j / 256, k = j % 256;
    W1_t[j] = (__bf16)W1[k * 1024 + n];
  } else {
    int j = idx - S1 - S2 - S3; int n = j / 1024, k = j % 1024;
    W2_t[j] = (__bf16)W2[k * 256 + n];
  }
  if (idx < 768) {
    int sel = idx >> 8, jj = idx & 255;
    const float* bsrc = (sel == 0) ? bq : (sel == 1) ? bk : bv;
    bqkv[idx] = bsrc[jj];
  }
}

// -------- MFMA GEMM: BM=128 x BN=128, BK=64, 4 waves (2x2 of 64x64), 32KB -----
// Per wave/phase: 16 ds_read_b128 feed 32 MFMA (FLOP/read = 32.8K, 1.5x the
// 32x64 tile). Single-buffer 2-barrier loop; TLP (3 blocks/CU) hides staging.
// AF32: A fp32, reg-staged with on-the-fly bf16 cvt. EPI: 0 bias, 1 bias+relu.
template <int EPI, bool AF32>
__global__ __launch_bounds__(256, 3) void gemm128_kernel(
    const void* __restrict__ Av, const __bf16* __restrict__ Bt,
    const float* __restrict__ bias, __hip_bfloat16* __restrict__ Y, int N, int K) {
  __shared__ __bf16 As[128 * 64];   // 16KB
  __shared__ __bf16 Bs[128 * 64];   // 16KB
  const int tid = threadIdx.x;
  const int lane = tid & 63, wv = tid >> 6;
  const int wm = wv >> 1, wn = wv & 1;
  const int gx = gridDim.x;
  const int nwg = gx * gridDim.y;
  int lin = blockIdx.y * gx + blockIdx.x;
  lin = (lin & 7) * (nwg >> 3) + (lin >> 3);
  const int n0 = (lin % gx) * 128;
  const int m0 = (lin / gx) * 128;
  const int fr = lane & 15, g = lane >> 4;
  const int lrow8 = lane >> 3;                               // 0..7
  const int gseg = ((lane & 7) ^ lrow8) * 8;                 // pre-swizzled src col

  f32x4 acc[4][4] = {};
  const int nph = K >> 6;

  for (int p = 0; p < nph; ++p) {
    const int kb = p * 64;
    __syncthreads();   // all waves done reading previous phase's LDS
    if (AF32) {
      const float* Af = (const float*)Av;
#pragma unroll
      for (int j = 0; j < 4; ++j) {
        const float* s0 = &Af[(size_t)(m0 + wv * 32 + j * 8 + lrow8) * K + kb + gseg];
        float4 a0 = *(const float4*)s0, a1 = *(const float4*)(s0 + 4);
        bf16x8 o = {(__bf16)a0.x, (__bf16)a0.y, (__bf16)a0.z, (__bf16)a0.w,
                    (__bf16)a1.x, (__bf16)a1.y, (__bf16)a1.z, (__bf16)a1.w};
        *(bf16x8*)&As[(wv * 32 + j * 8) * 64 + lane * 8] = o;
      }
    } else {
      const __bf16* Ab = (const __bf16*)Av;
#pragma unroll
      for (int j = 0; j < 4; ++j)
        gload16(Ab + (size_t)(m0 + wv * 32 + j * 8 + lrow8) * K + kb + gseg,
                &As[(wv * 32 + j * 8) * 64]);
    }
#pragma unroll
    for (int j = 0; j < 4; ++j)
      gload16(Bt + (size_t)(n0 + wv * 32 + j * 8 + lrow8) * K + kb + gseg,
              &Bs[(wv * 32 + j * 8) * 64]);
    __syncthreads();   // drains vmcnt + lgkmcnt: staged data visible
#pragma unroll
    for (int s = 0; s < 2; ++s) {
      bf16x8 av[4], bv[4];
      const int cs = ((s * 4 + g) ^ (fr & 7)) * 8;
#pragma unroll
      for (int mi = 0; mi < 4; ++mi)
        av[mi] = *reinterpret_cast<const bf16x8*>(&As[(wm * 64 + mi * 16 + fr) * 64 + cs]);
#pragma unroll
      for (int ni = 0; ni < 4; ++ni)
        bv[ni] = *reinterpret_cast<const bf16x8*>(&Bs[(wn * 64 + ni * 16 + fr) * 64 + cs]);
#pragma unroll
      for (int mi = 0; mi < 4; ++mi)
#pragma unroll
        for (int ni = 0; ni < 4; ++ni)
          acc[mi][ni] = __builtin_amdgcn_mfma_f32_16x16x32_bf16(av[mi], bv[ni], acc[mi][ni], 0, 0, 0);
    }
  }

  // epilogue: C/D layout col=lane&15, row=(lane>>4)*4+reg
  const int crow = m0 + wm * 64 + g * 4;
  const int ccol = n0 + wn * 64 + fr;
#pragma unroll
  for (int mi = 0; mi < 4; ++mi) {
#pragma unroll
    for (int ni = 0; ni < 4; ++ni) {
      const int col = ccol + ni * 16;
      const float bb = bias[col];
#pragma unroll
      for (int r = 0; r < 4; ++r) {
        const int row = crow + mi * 16 + r;
        float v = acc[mi][ni][r] + bb;
        if (EPI == 1) v = fmaxf(v, 0.f);
        Y[(size_t)row * N + col] = __float2bfloat16(v);
      }
    }
  }
}

// ---- GEMM (N=256) + bias + resid + LayerNorm: BM=64 x BN=256, 4 waves -------
// Wave grid 1x4, per-wave 64x64 (4x4 frags); all waves share the A-tile.
// LDS 42KB -> 3 blocks/CU; grid 576. LN block-local as before.
// RESID_F32: residual fp32 (table) vs bf16. OUT_F32: fp32 out (d_out) vs bf16.
template <bool RESID_F32, bool OUT_F32>
__global__ __launch_bounds__(256, 3) void gemm_ln256_kernel(
    const __bf16* __restrict__ A, const __bf16* __restrict__ Bt,
    const float* __restrict__ bias, const void* __restrict__ residv,
    const float* __restrict__ gamma, const float* __restrict__ beta,
    void* __restrict__ Y, int K) {
  __shared__ __bf16 As[64 * 64];    // 8KB
  __shared__ __bf16 Bs[256 * 64];   // 32KB
  __shared__ float red[2][4][64];   // {sum,sumsq}[wave][row]  (2KB)
  const int tid = threadIdx.x;
  const int lane = tid & 63, wv = tid >> 6;       // wv = wn 0..3
  const int nwg = gridDim.x;
  int lin = blockIdx.x;
  lin = (lin & 7) * (nwg >> 3) + (lin >> 3);
  const int m0 = lin * 64;
  const int fr = lane & 15, g = lane >> 4;
  const int lrow8 = lane >> 3;
  const int gseg = ((lane & 7) ^ lrow8) * 8;

  f32x4 acc[4][4] = {};
  const int nph = K >> 6;

  for (int p = 0; p < nph; ++p) {
    const int kb = p * 64;
    __syncthreads();
    // A: 64 rows; wave wv stages rows wv*16..+15 (2 gload16/thread)
    gload16(A + (size_t)(m0 + wv * 16 + lrow8) * K + kb + gseg,     &As[wv * 1024]);
    gload16(A + (size_t)(m0 + wv * 16 + 8 + lrow8) * K + kb + gseg, &As[wv * 1024 + 512]);
    // B: 256 rows; wave wv stages rows wv*64..+63 (8 gload16/thread)
#pragma unroll
    for (int j = 0; j < 8; ++j)
      gload16(Bt + (size_t)(wv * 64 + j * 8 + lrow8) * K + kb + gseg,
              &Bs[wv * 4096 + j * 512]);
    __syncthreads();
#pragma unroll
    for (int s = 0; s < 2; ++s) {
      bf16x8 av[4], bv[4];
      const int cs = ((s * 4 + g) ^ (fr & 7)) * 8;
#pragma unroll
      for (int mi = 0; mi < 4; ++mi)
        av[mi] = *reinterpret_cast<const bf16x8*>(&As[(mi * 16 + fr) * 64 + cs]);
#pragma unroll
      for (int ni = 0; ni < 4; ++ni)
        bv[ni] = *reinterpret_cast<const bf16x8*>(&Bs[(wv * 64 + ni * 16 + fr) * 64 + cs]);
#pragma unroll
      for (int mi = 0; mi < 4; ++mi)
#pragma unroll
        for (int ni = 0; ni < 4; ++ni)
          acc[mi][ni] = __builtin_amdgcn_mfma_f32_16x16x32_bf16(av[mi], bv[ni], acc[mi][ni], 0, 0, 0);
    }
  }

  // ---- epilogue: v = acc + bias + resid; LN over 256 cols per row ----
  const int colb = wv * 64 + fr;  // + ni*16
  float bb[4], gg[4], be[4];
#pragma unroll
  for (int ni = 0; ni < 4; ++ni) {
    bb[ni] = bias[colb + ni * 16];
    gg[ni] = gamma[colb + ni * 16];
    be[ni] = beta[colb + ni * 16];
  }
#pragma unroll
  for (int mi = 0; mi < 4; ++mi) {
#pragma unroll
    for (int r = 0; r < 4; ++r) {
      const int lr = mi * 16 + g * 4 + r;          // 0..63
      const size_t grow = (size_t)(m0 + lr) * 256;
      float s = 0.f, q = 0.f;
#pragma unroll
      for (int ni = 0; ni < 4; ++ni) {
        const int col = colb + ni * 16;
        const float rr = RESID_F32 ? ((const float*)residv)[grow + col]
                                   : (float)((const __bf16*)residv)[grow + col];
        float v = acc[mi][ni][r] + bb[ni] + rr;
        acc[mi][ni][r] = v;
        s += v; q += v * v;
      }
#pragma unroll
      for (int o = 8; o > 0; o >>= 1) { s += __shfl_xor(s, o); q += __shfl_xor(q, o); }
      if (fr == 0) { red[0][wv][lr] = s; red[1][wv][lr] = q; }
    }
  }
  __syncthreads();
#pragma unroll
  for (int mi = 0; mi < 4; ++mi) {
#pragma unroll
    for (int r = 0; r < 4; ++r) {
      const int lr = mi * 16 + g * 4 + r;
      const size_t grow = (size_t)(m0 + lr) * 256;
      const float s = red[0][0][lr] + red[0][1][lr] + red[0][2][lr] + red[0][3][lr];
      const float q = red[1][0][lr] + red[1][1][lr] + red[1][2][lr] + red[1][3][lr];
      const float mean = s * (1.0f / 256.0f);
      const float var = q * (1.0f / 256.0f) - mean * mean;
      const float inv = rsqrtf(var + 1e-5f);
#pragma unroll
      for (int ni = 0; ni < 4; ++ni) {
        const float y = (acc[mi][ni][r] - mean) * inv * gg[ni] + be[ni];
        if (OUT_F32) ((float*)Y)[grow + colb + ni * 16] = y;
        else ((__hip_bfloat16*)Y)[grow + colb + ni * 16] = __float2bfloat16(y);
      }
    }
  }
}

// ---------------- MFMA attention: one block per (b,h,x), 6 waves ----------------
__global__ __launch_bounds__(384) void attn_mfma_kernel(
    const __bf16* __restrict__ qkv, const float* __restrict__ depm,
    const float* __restrict__ Wdep, const float* __restrict__ bdep,
    __hip_bfloat16* __restrict__ ctx) {
  __shared__ __bf16 Qs[96][40];
  __shared__ __bf16 Ks[96][40];
  __shared__ __bf16 Vt[32][104];
  __shared__ __bf16 Ps[6][16][104];
  int lin = blockIdx.x;
  lin = (lin & 7) * 384 + (lin >> 3);
  const int h = lin & 7;
  const int sx = lin >> 3;
  const int x = sx % 96;
  const int b = sx / 96;
  const int tid = threadIdx.x;
  const size_t slab = (size_t)(b * 96 + x) * 96;
  const size_t base = slab * 768 + h * 32;
#pragma unroll
  for (int t = 0; t < 3; ++t) {
    const int idx = tid + t * 384;
    const int r = idx / 12, rem = idx % 12, mat = rem >> 2, seg = rem & 3;
    const int d0 = seg * 8;
    bf16x8 v8 = *(const bf16x8*)&qkv[base + (size_t)r * 768 + mat * 256 + d0];
    if (mat == 0)      *(bf16x8*)&Qs[r][d0] = v8;
    else if (mat == 1) *(bf16x8*)&Ks[r][d0] = v8;
    else {
#pragma unroll
      for (int e = 0; e < 8; ++e) Vt[d0 + e][r] = v8[e];
    }
  }
  __syncthreads();
  const int wave = tid >> 6, lane = tid & 63;
  const int fr = lane & 15, g = lane >> 4;
  const int q0 = wave * 16;
  const float wd = Wdep[h], bd = bdep[h];
  float depb[6];
#pragma unroll
  for (int f = 0; f < 6; ++f) depb[f] = depm[slab + fr + 16 * f] * wd + bd;
  const bf16x8 av = *(const bf16x8*)&Qs[q0 + fr][g * 8];
  f32x4 sacc[6];
#pragma unroll
  for (int f = 0; f < 6; ++f) {
    const bf16x8 bv = *(const bf16x8*)&Ks[f * 16 + fr][g * 8];
    sacc[f] = __builtin_amdgcn_mfma_f32_16x16x32_bf16(av, bv, (f32x4){0.f, 0.f, 0.f, 0.f}, 0, 0, 0);
  }
  const float scale = 0.17677669529663687f;
  float ev[6][4];
  float inv[4];
#pragma unroll
  for (int r = 0; r < 4; ++r) {
    float m = -1e30f;
#pragma unroll
    for (int f = 0; f < 6; ++f) {
      ev[f][r] = sacc[f][r] * scale + depb[f];
      m = fmaxf(m, ev[f][r]);
    }
#pragma unroll
    for (int o = 8; o > 0; o >>= 1) m = fmaxf(m, __shfl_xor(m, o));
    float sum = 0.f;
#pragma unroll
    for (int f = 0; f < 6; ++f) { ev[f][r] = __expf(ev[f][r] - m); sum += ev[f][r]; }
#pragma unroll
    for (int o = 8; o > 0; o >>= 1) sum += __shfl_xor(sum, o);
    inv[r] = 1.0f / sum;
  }
#pragma unroll
  for (int f = 0; f < 6; ++f)
#pragma unroll
    for (int r = 0; r < 4; ++r)
      Ps[wave][g * 4 + r][fr + 16 * f] = (__bf16)ev[f][r];
  asm volatile("s_waitcnt lgkmcnt(0)" ::: "memory");
  f32x4 o0 = {0.f, 0.f, 0.f, 0.f}, o1 = {0.f, 0.f, 0.f, 0.f};
#pragma unroll
  for (int s = 0; s < 3; ++s) {
    const bf16x8 pa  = *(const bf16x8*)&Ps[wave][fr][s * 32 + g * 8];
    const bf16x8 vb0 = *(const bf16x8*)&Vt[fr][s * 32 + g * 8];
    const bf16x8 vb1 = *(const bf16x8*)&Vt[16 + fr][s * 32 + g * 8];
    o0 = __builtin_amdgcn_mfma_f32_16x16x32_bf16(pa, vb0, o0, 0, 0, 0);
    o1 = __builtin_amdgcn_mfma_f32_16x16x32_bf16(pa, vb1, o1, 0, 0, 0);
  }
  const size_t orow = (slab + q0 + g * 4) * 256 + h * 32;
#pragma unroll
  for (int r = 0; r < 4; ++r) {
    ctx[orow + (size_t)r * 256 + fr]      = __float2bfloat16(o0[r] * inv[r]);
    ctx[orow + (size_t)r * 256 + 16 + fr] = __float2bfloat16(o1[r] * inv[r]);
  }
}

extern "C" void kernel_launch(void* const* d_in, const int* in_sizes, int n_in,
                              void* d_out, int out_size, void* d_ws, size_t ws_size,
                              hipStream_t stream) {
  (void)in_sizes; (void)n_in; (void)out_size; (void)ws_size;
  const float* table = (const float*)d_in[0];
  const float* depm  = (const float*)d_in[1];
  const float* Wq = (const float*)d_in[2];   const float* bq = (const float*)d_in[3];
  const float* Wk = (const float*)d_in[4];   const float* bk = (const float*)d_in[5];
  const float* Wv = (const float*)d_in[6];   const float* bv = (const float*)d_in[7];
  const float* Wo = (const float*)d_in[8];   const float* bo = (const float*)d_in[9];
  const float* Wdep = (const float*)d_in[10]; const float* bdep = (const float*)d_in[11];
  const float* g1 = (const float*)d_in[12];  const float* be1 = (const float*)d_in[13];
  const float* W1 = (const float*)d_in[14];  const float* b1 = (const float*)d_in[15];
  const float* W2 = (const float*)d_in[16];  const float* b2 = (const float*)d_in[17];
  const float* g2 = (const float*)d_in[18];  const float* be2 = (const float*)d_in[19];

  char* ws = (char*)d_ws;
  size_t off = 0;
  __bf16* qkvb  = (__bf16*)(ws + off); off += (size_t)M_ROWS * 768 * 2;   // 56.6MB
  __bf16* ctxb  = (__bf16*)(ws + off); off += (size_t)M_ROWS * 256 * 2;   // 18.9MB
  __bf16* outbb = (__bf16*)(ws + off); off += (size_t)M_ROWS * 256 * 2;   // 18.9MB
  __bf16* hidb  = (__bf16*)(ws + off); off += (size_t)M_ROWS * 1024 * 2;  // 75.5MB
  __bf16* Wqkv_t = (__bf16*)(ws + off); off += 768 * 256 * 2;
  __bf16* Wo_t   = (__bf16*)(ws + off); off += 256 * 256 * 2;
  __bf16* W1_t   = (__bf16*)(ws + off); off += 1024 * 256 * 2;
  __bf16* W2_t   = (__bf16*)(ws + off); off += 256 * 1024 * 2;
  float*  bqkv   = (float*)(ws + off);

  pack_w_kernel<<<3072, 256, 0, stream>>>(Wq, Wk, Wv, Wo, W1, W2, bq, bk, bv,
                                          Wqkv_t, Wo_t, W1_t, W2_t, bqkv);
  // qkv = table(fp32, reg-staged cvt) @ Wqkv + bqkv -> bf16 [M,768]
  gemm128_kernel<0, true><<<dim3(6, 288), 256, 0, stream>>>(
      table, Wqkv_t, bqkv, (__hip_bfloat16*)qkvb, 768, 256);
  // attention -> ctx bf16 [M,256]
  attn_mfma_kernel<<<3072, 384, 0, stream>>>(qkvb, depm, Wdep, bdep, (__hip_bfloat16*)ctxb);
  // outbb = LN1(ctx @ Wo + bo + table[fp32 resid])  [fused, bf16 out]
  gemm_ln256_kernel<true, false><<<576, 256, 0, stream>>>(
      ctxb, Wo_t, bo, table, g1, be1, outbb, 256);
  // hidden = relu(outbb @ W1 + b1) -> bf16 [M,1024]
  gemm128_kernel<1, false><<<dim3(8, 288), 256, 0, stream>>>(
      outbb, W1_t, b1, (__hip_bfloat16*)hidb, 1024, 256);
  // d_out = LN2(hidden @ W2 + b2 + outbb[bf16 resid])  [fused, fp32 out]
  gemm_ln256_kernel<false, true><<<576, 256, 0, stream>>>(
      hidb, W2_t, b2, outbb, g2, be2, (float*)d_out, 1024);
}